// Round 2
// baseline (7933.720 us; speedup 1.0000x reference)
//
#include <hip/hip_runtime.h>
#include <hip/hip_bf16.h>

#define D 128

// ---------------- degree: deg[src] += w ----------------
__global__ __launch_bounds__(256) void deg_kernel(const int* __restrict__ src,
                                                  const float* __restrict__ w,
                                                  float* __restrict__ deg, int E) {
    int e = blockIdx.x * 256 + threadIdx.x;
    if (e < E) atomicAdd(&deg[src[e]], w[e]);
}

// ---------------- scatter: agg[dst] += w * x[src] (wave per edge) ----------------
__global__ __launch_bounds__(256) void scatter_kernel(const float* __restrict__ xin,
                                                      const int* __restrict__ src,
                                                      const int* __restrict__ dst,
                                                      const float* __restrict__ w,
                                                      float* __restrict__ agg, int E) {
    int e = blockIdx.x * 4 + (threadIdx.x >> 6);
    if (e >= E) return;
    int lane = threadIdx.x & 63;
    int s = src[e], d = dst[e];
    float we = w[e];
    float2 v = *(const float2*)&xin[(size_t)s * D + 2 * lane];
    atomicAdd(&agg[(size_t)d * D + 2 * lane], we * v.x);
    atomicAdd(&agg[(size_t)d * D + 2 * lane + 1], we * v.y);
}

// ---------------- fused GraphConv linear: out = relu(A1@W1 + A2@W2 + b) ----------------
// 64x64 output tile per block, concat-K = 256 (two 128-K GEMMs), k-tiles of 64.
__global__ __launch_bounds__(256) void lin_kernel(const float* __restrict__ A1,
                                                  const float* __restrict__ A2,
                                                  const float* __restrict__ W1,
                                                  const float* __restrict__ W2,
                                                  const float* __restrict__ b,
                                                  float* __restrict__ out, int N) {
    __shared__ float As[64][68];   // +4 pad: breaks same-bank rows
    __shared__ float Ws[64 * 64];
    int tid = threadIdx.x;
    int c0 = (blockIdx.x & 1) * 64;
    int r0 = (blockIdx.x >> 1) * 64;
    int ty = tid >> 4, tx = tid & 15;

    float acc[4][4];
#pragma unroll
    for (int i = 0; i < 4; ++i)
#pragma unroll
        for (int j = 0; j < 4; ++j) acc[i][j] = 0.f;

#pragma unroll
    for (int t = 0; t < 4; ++t) {
        const float* A = (t < 2) ? A1 : A2;
        const float* W = (t < 2) ? W1 : W2;
        int kt = (t & 1) * 64;
        __syncthreads();
        // stage A tile: 64 rows x 64 k
#pragma unroll
        for (int i = 0; i < 4; ++i) {
            int f4 = tid + i * 256;       // 1024 float4
            int row = f4 >> 4;            // 16 float4 per row
            int c4 = f4 & 15;
            float4 v = make_float4(0.f, 0.f, 0.f, 0.f);
            if (r0 + row < N) v = *(const float4*)&A[(size_t)(r0 + row) * D + kt + c4 * 4];
            *(float4*)&As[row][c4 * 4] = v;
        }
        // stage W tile: 64 k x 64 cols
#pragma unroll
        for (int i = 0; i < 4; ++i) {
            int f4 = tid + i * 256;
            int k = f4 >> 4;
            int c4 = f4 & 15;
            *(float4*)&Ws[k * 64 + c4 * 4] = *(const float4*)&W[(size_t)(kt + k) * D + c0 + c4 * 4];
        }
        __syncthreads();
#pragma unroll
        for (int k = 0; k < 64; ++k) {
            float4 wv = *(const float4*)&Ws[k * 64 + tx * 4];
#pragma unroll
            for (int i = 0; i < 4; ++i) {
                float a = As[ty * 4 + i][k];
                acc[i][0] += a * wv.x;
                acc[i][1] += a * wv.y;
                acc[i][2] += a * wv.z;
                acc[i][3] += a * wv.w;
            }
        }
    }
    float4 bv = *(const float4*)&b[c0 + tx * 4];
#pragma unroll
    for (int i = 0; i < 4; ++i) {
        int r = r0 + ty * 4 + i;
        if (r < N) {
            float4 v;
            v.x = fmaxf(acc[i][0] + bv.x, 0.f);
            v.y = fmaxf(acc[i][1] + bv.y, 0.f);
            v.z = fmaxf(acc[i][2] + bv.z, 0.f);
            v.w = fmaxf(acc[i][3] + bv.w, 0.f);
            *(float4*)&out[(size_t)r * D + c0 + tx * 4] = v;
        }
    }
}

// ---------------- Wc = W_m1 @ W_out ; bc = b_m1 @ W_out + b_out ----------------
__global__ __launch_bounds__(256) void smallmm_kernel(const float* __restrict__ Wm1,
                                                      const float* __restrict__ bm1,
                                                      const float* __restrict__ Wout,
                                                      const float* __restrict__ bout,
                                                      float* __restrict__ Wc,
                                                      float* __restrict__ bc) {
    int idx = blockIdx.x * 256 + threadIdx.x;
    if (blockIdx.x < 64) {
        int i = idx >> 7, j = idx & 127;
        float s = 0.f;
        for (int k = 0; k < 128; ++k) s += Wm1[i * 128 + k] * Wout[k * 128 + j];
        Wc[idx] = s;
    } else {
        int j = threadIdx.x;
        if (j < 128) {
            float s = bout[j];
            for (int k = 0; k < 128; ++k) s += bm1[k] * Wout[k * 128 + j];
            bc[j] = s;
        }
    }
}

// ---------------- s = h2@Wc + bc, softmax -> probs; den += deg[r]*||p||^2 ----------------
// 32 rows per block, wave-per-row (wave handles rows wave, wave+4, ...);
// each lane owns ONE column of each 64-col half of Wc (staged in LDS).
// Safe to run in-place (h2 == probs): all reads of h2 go through Rs, staged
// before any write, and blocks touch disjoint rows.
__global__ __launch_bounds__(256) void out_softmax_kernel(const float* __restrict__ h2,
                                                          const float* __restrict__ Wc,
                                                          const float* __restrict__ bc,
                                                          const float* __restrict__ deg,
                                                          float* __restrict__ probs,
                                                          float* __restrict__ accum, int N) {
    __shared__ float Rs[32][128];   // 16 KB
    __shared__ float Ws[128 * 64];  // 32 KB
    int tid = threadIdx.x;
    int wave = tid >> 6, lane = tid & 63;
    int r0 = blockIdx.x * 32;
    // stage 32 rows of h2
#pragma unroll
    for (int i = 0; i < 4; ++i) {
        int f4 = tid + i * 256;   // 1024 float4
        int row = f4 >> 5;        // 32 float4 per row
        int c4 = f4 & 31;
        float4 v = make_float4(0.f, 0.f, 0.f, 0.f);
        if (r0 + row < N) v = *(const float4*)&h2[(size_t)(r0 + row) * D + c4 * 4];
        *(float4*)&Rs[row][c4 * 4] = v;
    }
    float lg[8][2];
#pragma unroll
    for (int h = 0; h < 2; ++h) {
        __syncthreads();   // protect Ws reuse (and Rs staging on h==0)
#pragma unroll
        for (int i = 0; i < 8; ++i) {
            int f4 = tid + i * 256;   // 2048 float4
            int k = f4 >> 4;          // 16 float4 per k row
            int c4 = f4 & 15;
            *(float4*)&Ws[k * 64 + c4 * 4] = *(const float4*)&Wc[(size_t)k * 128 + h * 64 + c4 * 4];
        }
        __syncthreads();
        float bv = bc[h * 64 + lane];
        float a[8];
#pragma unroll
        for (int ri = 0; ri < 8; ++ri) a[ri] = bv;
        for (int k = 0; k < 128; ++k) {
            float wv = Ws[k * 64 + lane];
#pragma unroll
            for (int ri = 0; ri < 8; ++ri) a[ri] += Rs[wave + ri * 4][k] * wv;
        }
#pragma unroll
        for (int ri = 0; ri < 8; ++ri) lg[ri][h] = a[ri];
    }
    float den_local = 0.f;
#pragma unroll
    for (int ri = 0; ri < 8; ++ri) {
        int row = wave + ri * 4;
        int gr = r0 + row;
        float m = fmaxf(lg[ri][0], lg[ri][1]);
#pragma unroll
        for (int s = 32; s >= 1; s >>= 1) m = fmaxf(m, __shfl_xor(m, s));
        float e0 = expf(lg[ri][0] - m);
        float e1 = expf(lg[ri][1] - m);
        float sum = e0 + e1;
#pragma unroll
        for (int s = 32; s >= 1; s >>= 1) sum += __shfl_xor(sum, s);
        float inv = 1.f / sum;
        float p0 = e0 * inv, p1 = e1 * inv;
        float sq = p0 * p0 + p1 * p1;
#pragma unroll
        for (int s = 32; s >= 1; s >>= 1) sq += __shfl_xor(sq, s);
        if (gr < N) {
            probs[(size_t)gr * D + lane]      = p0;
            probs[(size_t)gr * D + 64 + lane] = p1;
            if (lane == 0) den_local += deg[gr] * sq;
        }
    }
    if (lane == 0 && den_local != 0.f) atomicAdd(&accum[1], den_local);
}

// ---------------- mincut_num = sum_e w_e * <p[src], p[dst]> ----------------
__global__ __launch_bounds__(256) void num_kernel(const float* __restrict__ probs,
                                                  const int* __restrict__ src,
                                                  const int* __restrict__ dst,
                                                  const float* __restrict__ w,
                                                  float* __restrict__ accum, int E) {
    int tid = threadIdx.x;
    int wave = tid >> 6, lane = tid & 63;
    float acc = 0.f;
    int stride = gridDim.x * 4;
    for (int e = blockIdx.x * 4 + wave; e < E; e += stride) {
        int s = src[e], d = dst[e];
        float we = w[e];
        float2 ps = *(const float2*)&probs[(size_t)s * D + 2 * lane];
        float2 pd = *(const float2*)&probs[(size_t)d * D + 2 * lane];
        acc += we * (ps.x * pd.x + ps.y * pd.y);
    }
#pragma unroll
    for (int m = 32; m >= 1; m >>= 1) acc += __shfl_xor(acc, m);
    __shared__ float wsum[4];
    if (lane == 0) wsum[wave] = acc;
    __syncthreads();
    if (tid == 0) atomicAdd(&accum[0], wsum[0] + wsum[1] + wsum[2] + wsum[3]);
}

// ---------------- ss += probs^T @ probs (per-thread 64 accumulators) ----------------
__global__ __launch_bounds__(256) void ss_kernel(const float* __restrict__ probs,
                                                 float* __restrict__ ss, int N) {
    __shared__ float Ps[128];
    int tid = threadIdx.x;
    int a = tid >> 1;
    int boff = (tid & 1) * 64;
    float acc[64];
#pragma unroll
    for (int j = 0; j < 64; ++j) acc[j] = 0.f;
    for (int r = blockIdx.x; r < N; r += gridDim.x) {
        __syncthreads();
        if (tid < 32) *(float4*)&Ps[tid * 4] = *(const float4*)&probs[(size_t)r * D + tid * 4];
        __syncthreads();
        float pa = Ps[a];
#pragma unroll
        for (int j = 0; j < 64; ++j) acc[j] += pa * Ps[boff + j];
    }
#pragma unroll
    for (int j = 0; j < 64; ++j) atomicAdd(&ss[a * 128 + boff + j], acc[j]);
}

// ---------------- finalize: mc_loss, o_loss ----------------
__global__ __launch_bounds__(256) void finalize_kernel(const float* __restrict__ ss,
                                                       const float* __restrict__ accum,
                                                       float* __restrict__ out2) {
    int tid = threadIdx.x;
    __shared__ float wsum[4], wsum2[4];
    float s = 0.f;
    for (int i = tid; i < 16384; i += 256) { float v = ss[i]; s += v * v; }
#pragma unroll
    for (int m = 32; m >= 1; m >>= 1) s += __shfl_xor(s, m);
    if ((tid & 63) == 0) wsum[tid >> 6] = s;
    __syncthreads();
    float norm = sqrtf(wsum[0] + wsum[1] + wsum[2] + wsum[3]);
    float inv = 1.f / norm;
    const float rk = 0.08838834764831845f;  // 1/sqrt(128)
    float o = 0.f;
    for (int i = tid; i < 16384; i += 256) {
        int a = i >> 7, b = i & 127;
        float v = ss[i] * inv - (a == b ? rk : 0.f);
        o += v * v;
    }
#pragma unroll
    for (int m = 32; m >= 1; m >>= 1) o += __shfl_xor(o, m);
    if ((tid & 63) == 0) wsum2[tid >> 6] = o;
    __syncthreads();
    if (tid == 0) {
        out2[0] = -(accum[0] / accum[1]);
        out2[1] = sqrtf(wsum2[0] + wsum2[1] + wsum2[2] + wsum2[3]);
    }
}

extern "C" void kernel_launch(void* const* d_in, const int* in_sizes, int n_in,
                              void* d_out, int out_size, void* d_ws, size_t ws_size,
                              hipStream_t stream) {
    const float* x      = (const float*)d_in[0];
    const int*   ei     = (const int*)d_in[1];
    const float* w      = (const float*)d_in[2];
    const float* Wrel1  = (const float*)d_in[3];
    const float* brel1  = (const float*)d_in[4];
    const float* Wroot1 = (const float*)d_in[5];
    const float* Wrel2  = (const float*)d_in[6];
    const float* brel2  = (const float*)d_in[7];
    const float* Wroot2 = (const float*)d_in[8];
    const float* Wm1    = (const float*)d_in[9];
    const float* bm1    = (const float*)d_in[10];
    const float* Wout   = (const float*)d_in[11];
    const float* bout   = (const float*)d_in[12];

    int N = in_sizes[0] / D;
    int E = in_sizes[2];
    const int* src = ei;
    const int* dst = ei + E;

    float* probs = (float*)d_out;
    float* out2  = probs + (size_t)N * D;  // [mc_loss, o_loss]
    float* h2    = probs;                  // h2 lives in-place in d_out (see out_softmax)

    float* ws    = (float*)d_ws;
    float* agg   = ws;                     // N*D
    float* h1    = ws + (size_t)N * D;     // N*D
    float* Wc    = ws + (size_t)2 * N * D; // 16384
    float* bc    = Wc + 16384;             // 128
    float* ssb   = bc + 128;               // 16384
    float* deg   = ssb + 16384;            // N
    float* accum = deg + N;                // 2

    // zero accumulators (ssb, deg, accum are contiguous)
    hipMemsetAsync(agg, 0, (size_t)N * D * sizeof(float), stream);
    hipMemsetAsync(ssb, 0, (size_t)(16384 + N + 2) * sizeof(float), stream);

    int linGrid = ((N + 63) / 64) * 2;
    int scatGrid = (E + 3) / 4;

    deg_kernel<<<(E + 255) / 256, 256, 0, stream>>>(src, w, deg, E);
    scatter_kernel<<<scatGrid, 256, 0, stream>>>(x, src, dst, w, agg, E);
    lin_kernel<<<linGrid, 256, 0, stream>>>(agg, x, Wrel1, Wroot1, brel1, h1, N);
    hipMemsetAsync(agg, 0, (size_t)N * D * sizeof(float), stream);
    scatter_kernel<<<scatGrid, 256, 0, stream>>>(h1, src, dst, w, agg, E);
    lin_kernel<<<linGrid, 256, 0, stream>>>(agg, h1, Wrel2, Wroot2, brel2, h2, N);
    smallmm_kernel<<<65, 256, 0, stream>>>(Wm1, bm1, Wout, bout, Wc, bc);
    out_softmax_kernel<<<(N + 31) / 32, 256, 0, stream>>>(h2, Wc, bc, deg, probs, accum, N);
    num_kernel<<<2048, 256, 0, stream>>>(probs, src, dst, w, accum, E);
    ss_kernel<<<256, 256, 0, stream>>>(probs, ssb, N);
    finalize_kernel<<<1, 256, 0, stream>>>(ssb, accum, out2);
}

// Round 3
// 2163.352 us; speedup vs baseline: 3.6673x; 3.6673x over previous
//
#include <hip/hip_runtime.h>
#include <hip/hip_bf16.h>

#define D 128
#define KT 32

// ---------------- degree: deg[src] += w ----------------
__global__ __launch_bounds__(256) void deg_kernel(const int* __restrict__ src,
                                                  const float* __restrict__ w,
                                                  float* __restrict__ deg, int E) {
    int e = blockIdx.x * 256 + threadIdx.x;
    if (e < E) atomicAdd(&deg[src[e]], w[e]);
}

// ---------------- scatter: agg[dst] += w * x[src] (wave per edge) ----------------
__global__ __launch_bounds__(256) void scatter_kernel(const float* __restrict__ xin,
                                                      const int* __restrict__ src,
                                                      const int* __restrict__ dst,
                                                      const float* __restrict__ w,
                                                      float* __restrict__ agg, int E) {
    int e = blockIdx.x * 4 + (threadIdx.x >> 6);
    if (e >= E) return;
    int lane = threadIdx.x & 63;
    int s = src[e], d = dst[e];
    float we = w[e];
    float2 v = *(const float2*)&xin[(size_t)s * D + 2 * lane];
    atomicAdd(&agg[(size_t)d * D + 2 * lane], we * v.x);
    atomicAdd(&agg[(size_t)d * D + 2 * lane + 1], we * v.y);
}

// ---------------- fused GraphConv linear: out = relu(A1@W1 + A2@W2 + b) ----------------
// 128x128 tile per block (full width), 256 threads, 4 rows x 16 cols per thread.
// K = 256 (A1 then A2) in 8 k-tiles of 32. A staged TRANSPOSED As[k][row]
// (row-stride 132 words: 16B-aligned float4 reads, conflict-free banks).
#define FMA4(acc, a, wv) { acc.x += (a) * (wv).x; acc.y += (a) * (wv).y; \
                           acc.z += (a) * (wv).z; acc.w += (a) * (wv).w; }

__global__ __launch_bounds__(256) void lin_kernel(const float* __restrict__ A1,
                                                  const float* __restrict__ A2,
                                                  const float* __restrict__ W1,
                                                  const float* __restrict__ W2,
                                                  const float* __restrict__ b,
                                                  float* __restrict__ out, int N) {
    __shared__ float As[KT][132];   // transposed A tile: [k][row], 16.9 KB
    __shared__ float Ws[KT][D];     // [k][col], 16 KB
    int tid = threadIdx.x;
    int r0 = blockIdx.x * 128;
    int ty4 = (tid >> 3) * 4;       // row group: 4 rows
    int tx16 = (tid & 7) * 16;      // col group: 16 cols

    float4 acc[4][4];
#pragma unroll
    for (int i = 0; i < 4; ++i)
#pragma unroll
        for (int j = 0; j < 4; ++j) acc[i][j] = make_float4(0.f, 0.f, 0.f, 0.f);

    for (int t = 0; t < 8; ++t) {
        const float* A = (t < 4) ? A1 : A2;
        const float* W = (t < 4) ? W1 : W2;
        int koff = (t & 3) * KT;
        __syncthreads();
        // stage A tile transposed: 128 rows x 32 k = 1024 float4, 4 per thread
#pragma unroll
        for (int i = 0; i < 4; ++i) {
            int f4 = tid + i * 256;
            int row = f4 >> 3;      // 0..127
            int c4 = f4 & 7;        // k-quad
            float4 v = make_float4(0.f, 0.f, 0.f, 0.f);
            if (r0 + row < N) v = *(const float4*)&A[(size_t)(r0 + row) * D + koff + c4 * 4];
            As[c4 * 4 + 0][row] = v.x;
            As[c4 * 4 + 1][row] = v.y;
            As[c4 * 4 + 2][row] = v.z;
            As[c4 * 4 + 3][row] = v.w;
        }
        // stage W tile: 32 k x 128 cols = 1024 float4 (contiguous wave writes)
#pragma unroll
        for (int i = 0; i < 4; ++i) {
            int f4 = tid + i * 256;
            int k = f4 >> 5;
            int c4 = f4 & 31;
            *(float4*)&Ws[k][c4 * 4] = *(const float4*)&W[(size_t)(koff + k) * D + c4 * 4];
        }
        __syncthreads();
#pragma unroll 4
        for (int k = 0; k < KT; ++k) {
            float4 av = *(const float4*)&As[k][ty4];
            float4 w0 = *(const float4*)&Ws[k][tx16];
            float4 w1 = *(const float4*)&Ws[k][tx16 + 4];
            float4 w2 = *(const float4*)&Ws[k][tx16 + 8];
            float4 w3 = *(const float4*)&Ws[k][tx16 + 12];
            FMA4(acc[0][0], av.x, w0); FMA4(acc[0][1], av.x, w1);
            FMA4(acc[0][2], av.x, w2); FMA4(acc[0][3], av.x, w3);
            FMA4(acc[1][0], av.y, w0); FMA4(acc[1][1], av.y, w1);
            FMA4(acc[1][2], av.y, w2); FMA4(acc[1][3], av.y, w3);
            FMA4(acc[2][0], av.z, w0); FMA4(acc[2][1], av.z, w1);
            FMA4(acc[2][2], av.z, w2); FMA4(acc[2][3], av.z, w3);
            FMA4(acc[3][0], av.w, w0); FMA4(acc[3][1], av.w, w1);
            FMA4(acc[3][2], av.w, w2); FMA4(acc[3][3], av.w, w3);
        }
    }
    float4 bv[4];
#pragma unroll
    for (int j = 0; j < 4; ++j) bv[j] = *(const float4*)&b[tx16 + j * 4];
#pragma unroll
    for (int i = 0; i < 4; ++i) {
        int r = r0 + ty4 + i;
        if (r < N) {
#pragma unroll
            for (int j = 0; j < 4; ++j) {
                float4 v;
                v.x = fmaxf(acc[i][j].x + bv[j].x, 0.f);
                v.y = fmaxf(acc[i][j].y + bv[j].y, 0.f);
                v.z = fmaxf(acc[i][j].z + bv[j].z, 0.f);
                v.w = fmaxf(acc[i][j].w + bv[j].w, 0.f);
                *(float4*)&out[(size_t)r * D + tx16 + j * 4] = v;
            }
        }
    }
}

// ---------------- Wc = W_m1 @ W_out ; bc = b_m1 @ W_out + b_out ----------------
__global__ __launch_bounds__(256) void smallmm_kernel(const float* __restrict__ Wm1,
                                                      const float* __restrict__ bm1,
                                                      const float* __restrict__ Wout,
                                                      const float* __restrict__ bout,
                                                      float* __restrict__ Wc,
                                                      float* __restrict__ bc) {
    int idx = blockIdx.x * 256 + threadIdx.x;
    if (blockIdx.x < 64) {
        int i = idx >> 7, j = idx & 127;
        float s = 0.f;
        for (int k = 0; k < 128; ++k) s += Wm1[i * 128 + k] * Wout[k * 128 + j];
        Wc[idx] = s;
    } else {
        int j = threadIdx.x;
        if (j < 128) {
            float s = bout[j];
            for (int k = 0; k < 128; ++k) s += bm1[k] * Wout[k * 128 + j];
            bc[j] = s;
        }
    }
}

// ---------------- s = h2@Wc + bc, softmax -> probs; den += deg[r]*||p||^2 ----------------
// 32 rows per block, wave-per-row; each lane owns ONE column of each 64-col half.
// Safe in-place (h2 == probs): reads staged to Rs before writes, disjoint rows per block.
__global__ __launch_bounds__(256) void out_softmax_kernel(const float* __restrict__ h2,
                                                          const float* __restrict__ Wc,
                                                          const float* __restrict__ bc,
                                                          const float* __restrict__ deg,
                                                          float* __restrict__ probs,
                                                          float* __restrict__ accum, int N) {
    __shared__ float Rs[32][128];   // 16 KB
    __shared__ float Ws[128 * 64];  // 32 KB
    int tid = threadIdx.x;
    int wave = tid >> 6, lane = tid & 63;
    int r0 = blockIdx.x * 32;
#pragma unroll
    for (int i = 0; i < 4; ++i) {
        int f4 = tid + i * 256;
        int row = f4 >> 5;
        int c4 = f4 & 31;
        float4 v = make_float4(0.f, 0.f, 0.f, 0.f);
        if (r0 + row < N) v = *(const float4*)&h2[(size_t)(r0 + row) * D + c4 * 4];
        *(float4*)&Rs[row][c4 * 4] = v;
    }
    float lg[8][2];
#pragma unroll
    for (int h = 0; h < 2; ++h) {
        __syncthreads();
#pragma unroll
        for (int i = 0; i < 8; ++i) {
            int f4 = tid + i * 256;
            int k = f4 >> 4;
            int c4 = f4 & 15;
            *(float4*)&Ws[k * 64 + c4 * 4] = *(const float4*)&Wc[(size_t)k * 128 + h * 64 + c4 * 4];
        }
        __syncthreads();
        float bv = bc[h * 64 + lane];
        float a[8];
#pragma unroll
        for (int ri = 0; ri < 8; ++ri) a[ri] = bv;
        for (int k = 0; k < 128; ++k) {
            float wv = Ws[k * 64 + lane];
#pragma unroll
            for (int ri = 0; ri < 8; ++ri) a[ri] += Rs[wave + ri * 4][k] * wv;
        }
#pragma unroll
        for (int ri = 0; ri < 8; ++ri) lg[ri][h] = a[ri];
    }
    float den_local = 0.f;
#pragma unroll
    for (int ri = 0; ri < 8; ++ri) {
        int row = wave + ri * 4;
        int gr = r0 + row;
        float m = fmaxf(lg[ri][0], lg[ri][1]);
#pragma unroll
        for (int s = 32; s >= 1; s >>= 1) m = fmaxf(m, __shfl_xor(m, s));
        float e0 = expf(lg[ri][0] - m);
        float e1 = expf(lg[ri][1] - m);
        float sum = e0 + e1;
#pragma unroll
        for (int s = 32; s >= 1; s >>= 1) sum += __shfl_xor(sum, s);
        float inv = 1.f / sum;
        float p0 = e0 * inv, p1 = e1 * inv;
        float sq = p0 * p0 + p1 * p1;
#pragma unroll
        for (int s = 32; s >= 1; s >>= 1) sq += __shfl_xor(sq, s);
        if (gr < N) {
            probs[(size_t)gr * D + lane]      = p0;
            probs[(size_t)gr * D + 64 + lane] = p1;
            if (lane == 0) den_local += deg[gr] * sq;
        }
    }
    if (lane == 0 && den_local != 0.f) atomicAdd(&accum[1], den_local);
}

// ---------------- mincut_num = sum_e w_e * <p[src], p[dst]> ----------------
__global__ __launch_bounds__(256) void num_kernel(const float* __restrict__ probs,
                                                  const int* __restrict__ src,
                                                  const int* __restrict__ dst,
                                                  const float* __restrict__ w,
                                                  float* __restrict__ accum, int E) {
    int tid = threadIdx.x;
    int wave = tid >> 6, lane = tid & 63;
    float acc = 0.f;
    int stride = gridDim.x * 4;
    for (int e = blockIdx.x * 4 + wave; e < E; e += stride) {
        int s = src[e], d = dst[e];
        float we = w[e];
        float2 ps = *(const float2*)&probs[(size_t)s * D + 2 * lane];
        float2 pd = *(const float2*)&probs[(size_t)d * D + 2 * lane];
        acc += we * (ps.x * pd.x + ps.y * pd.y);
    }
#pragma unroll
    for (int m = 32; m >= 1; m >>= 1) acc += __shfl_xor(acc, m);
    __shared__ float wsum[4];
    if (lane == 0) wsum[wave] = acc;
    __syncthreads();
    if (tid == 0) atomicAdd(&accum[0], wsum[0] + wsum[1] + wsum[2] + wsum[3]);
}

// ---------------- ss += probs^T @ probs (per-thread 64 accumulators) ----------------
__global__ __launch_bounds__(256) void ss_kernel(const float* __restrict__ probs,
                                                 float* __restrict__ ss, int N) {
    __shared__ float Ps[128];
    int tid = threadIdx.x;
    int a = tid >> 1;
    int boff = (tid & 1) * 64;
    float acc[64];
#pragma unroll
    for (int j = 0; j < 64; ++j) acc[j] = 0.f;
    for (int r = blockIdx.x; r < N; r += gridDim.x) {
        __syncthreads();
        if (tid < 32) *(float4*)&Ps[tid * 4] = *(const float4*)&probs[(size_t)r * D + tid * 4];
        __syncthreads();
        float pa = Ps[a];
#pragma unroll
        for (int j = 0; j < 64; ++j) acc[j] += pa * Ps[boff + j];
    }
#pragma unroll
    for (int j = 0; j < 64; ++j) atomicAdd(&ss[a * 128 + boff + j], acc[j]);
}

// ---------------- finalize: mc_loss, o_loss ----------------
__global__ __launch_bounds__(256) void finalize_kernel(const float* __restrict__ ss,
                                                       const float* __restrict__ accum,
                                                       float* __restrict__ out2) {
    int tid = threadIdx.x;
    __shared__ float wsum[4], wsum2[4];
    float s = 0.f;
    for (int i = tid; i < 16384; i += 256) { float v = ss[i]; s += v * v; }
#pragma unroll
    for (int m = 32; m >= 1; m >>= 1) s += __shfl_xor(s, m);
    if ((tid & 63) == 0) wsum[tid >> 6] = s;
    __syncthreads();
    float norm = sqrtf(wsum[0] + wsum[1] + wsum[2] + wsum[3]);
    float inv = 1.f / norm;
    const float rk = 0.08838834764831845f;  // 1/sqrt(128)
    float o = 0.f;
    for (int i = tid; i < 16384; i += 256) {
        int a = i >> 7, b = i & 127;
        float v = ss[i] * inv - (a == b ? rk : 0.f);
        o += v * v;
    }
#pragma unroll
    for (int m = 32; m >= 1; m >>= 1) o += __shfl_xor(o, m);
    if ((tid & 63) == 0) wsum2[tid >> 6] = o;
    __syncthreads();
    if (tid == 0) {
        out2[0] = -(accum[0] / accum[1]);
        out2[1] = sqrtf(wsum2[0] + wsum2[1] + wsum2[2] + wsum2[3]);
    }
}

extern "C" void kernel_launch(void* const* d_in, const int* in_sizes, int n_in,
                              void* d_out, int out_size, void* d_ws, size_t ws_size,
                              hipStream_t stream) {
    const float* x      = (const float*)d_in[0];
    const int*   ei     = (const int*)d_in[1];
    const float* w      = (const float*)d_in[2];
    const float* Wrel1  = (const float*)d_in[3];
    const float* brel1  = (const float*)d_in[4];
    const float* Wroot1 = (const float*)d_in[5];
    const float* Wrel2  = (const float*)d_in[6];
    const float* brel2  = (const float*)d_in[7];
    const float* Wroot2 = (const float*)d_in[8];
    const float* Wm1    = (const float*)d_in[9];
    const float* bm1    = (const float*)d_in[10];
    const float* Wout   = (const float*)d_in[11];
    const float* bout   = (const float*)d_in[12];

    int N = in_sizes[0] / D;
    int E = in_sizes[2];
    const int* src = ei;
    const int* dst = ei + E;

    float* probs = (float*)d_out;
    float* out2  = probs + (size_t)N * D;  // [mc_loss, o_loss]
    float* h2    = probs;                  // h2 lives in-place in d_out

    float* ws    = (float*)d_ws;
    float* agg   = ws;                     // N*D
    float* h1    = ws + (size_t)N * D;     // N*D
    float* Wc    = ws + (size_t)2 * N * D; // 16384
    float* bc    = Wc + 16384;             // 128
    float* ssb   = bc + 128;               // 16384
    float* deg   = ssb + 16384;            // N
    float* accum = deg + N;                // 2

    hipMemsetAsync(agg, 0, (size_t)N * D * sizeof(float), stream);
    hipMemsetAsync(ssb, 0, (size_t)(16384 + N + 2) * sizeof(float), stream);

    int linGrid = (N + 127) / 128;
    int scatGrid = (E + 3) / 4;

    deg_kernel<<<(E + 255) / 256, 256, 0, stream>>>(src, w, deg, E);
    scatter_kernel<<<scatGrid, 256, 0, stream>>>(x, src, dst, w, agg, E);
    lin_kernel<<<linGrid, 256, 0, stream>>>(agg, x, Wrel1, Wroot1, brel1, h1, N);
    hipMemsetAsync(agg, 0, (size_t)N * D * sizeof(float), stream);
    scatter_kernel<<<scatGrid, 256, 0, stream>>>(h1, src, dst, w, agg, E);
    lin_kernel<<<linGrid, 256, 0, stream>>>(agg, h1, Wrel2, Wroot2, brel2, h2, N);
    smallmm_kernel<<<65, 256, 0, stream>>>(Wm1, bm1, Wout, bout, Wc, bc);
    out_softmax_kernel<<<(N + 31) / 32, 256, 0, stream>>>(h2, Wc, bc, deg, probs, accum, N);
    num_kernel<<<2048, 256, 0, stream>>>(probs, src, dst, w, accum, E);
    ss_kernel<<<256, 256, 0, stream>>>(probs, ssb, N);
    finalize_kernel<<<1, 256, 0, stream>>>(ssb, accum, out2);
}

// Round 4
// 1105.211 us; speedup vs baseline: 7.1785x; 1.9574x over previous
//
#include <hip/hip_runtime.h>
#include <hip/hip_bf16.h>

#define D 128
#define KT 32

// ---------------- degree: deg[src] += w ----------------
__global__ __launch_bounds__(256) void deg_kernel(const int* __restrict__ src,
                                                  const float* __restrict__ w,
                                                  float* __restrict__ deg, int E) {
    int e = blockIdx.x * 256 + threadIdx.x;
    if (e < E) atomicAdd(&deg[src[e]], w[e]);
}

// ---------------- CSR build: histogram of dst ----------------
__global__ __launch_bounds__(256) void hist_kernel(const int* __restrict__ dst,
                                                   int* __restrict__ cnt, int E) {
    int e = blockIdx.x * 256 + threadIdx.x;
    if (e < E) atomicAdd(&cnt[dst[e]], 1);
}

// ---------------- CSR build: per-1024-chunk inclusive scan ----------------
// rowptr[i+1] = inclusive scan of cnt within chunk; aux[b] = chunk total.
__global__ __launch_bounds__(256) void scan_chunk_kernel(const int* __restrict__ cnt,
                                                         int* __restrict__ rowptr,
                                                         int* __restrict__ aux, int N) {
    __shared__ int ts[256];
    int t = threadIdx.x;
    int base = blockIdx.x * 1024 + t * 4;
    int v[4], s = 0;
#pragma unroll
    for (int i = 0; i < 4; ++i) {
        v[i] = (base + i < N) ? cnt[base + i] : 0;
        s += v[i];
    }
    ts[t] = s;
    __syncthreads();
#pragma unroll
    for (int off = 1; off < 256; off <<= 1) {
        int add = (t >= off) ? ts[t - off] : 0;
        __syncthreads();
        ts[t] += add;
        __syncthreads();
    }
    int run = ts[t] - s;   // exclusive prefix of this thread
#pragma unroll
    for (int i = 0; i < 4; ++i) {
        run += v[i];
        if (base + i < N) rowptr[base + i + 1] = run;
    }
    if (t == 255) aux[blockIdx.x] = ts[255];
}

// ---------------- CSR build: scan chunk totals (single block, serial) ----------------
__global__ void scan_aux_kernel(int* __restrict__ aux, int nb) {
    if (threadIdx.x == 0) {
        int s = 0;
        for (int i = 0; i < nb; ++i) { s += aux[i]; aux[i] = s; }
    }
}

// ---------------- CSR build: add chunk offsets ----------------
__global__ __launch_bounds__(256) void add_off_kernel(int* __restrict__ rowptr,
                                                      const int* __restrict__ aux, int N) {
    int i = blockIdx.x * 256 + threadIdx.x;
    if (i == 0) rowptr[0] = 0;
    if (i < N) {
        int b = i >> 10;
        if (b > 0) rowptr[i + 1] += aux[b - 1];
    }
}

// ---------------- CSR build: fill edge slots ----------------
__global__ __launch_bounds__(256) void fill_kernel(const int* __restrict__ src,
                                                   const int* __restrict__ dst,
                                                   const float* __restrict__ w,
                                                   const int* __restrict__ rowptr,
                                                   int* __restrict__ cur,
                                                   int* __restrict__ csr_src,
                                                   float* __restrict__ csr_w, int E) {
    int e = blockIdx.x * 256 + threadIdx.x;
    if (e < E) {
        int d = dst[e];
        int pos = rowptr[d] + atomicAdd(&cur[d], 1);
        csr_src[pos] = src[e];
        csr_w[pos] = w[e];
    }
}

// ---------------- gather: agg[n] = sum_{e in row n} w_e * x[src_e] ----------------
// Wave per node, 2 feature elems per lane, no atomics, coalesced writes.
__global__ __launch_bounds__(256) void gather_kernel(const float* __restrict__ xin,
                                                     const int* __restrict__ csr_src,
                                                     const float* __restrict__ csr_w,
                                                     const int* __restrict__ rowptr,
                                                     float* __restrict__ agg, int N) {
    int node = blockIdx.x * 4 + (threadIdx.x >> 6);
    if (node >= N) return;
    int lane = threadIdx.x & 63;
    int beg = rowptr[node], end = rowptr[node + 1];
    float a0 = 0.f, a1 = 0.f;
    int j = beg;
    for (; j + 1 < end; j += 2) {
        int s0 = csr_src[j], s1 = csr_src[j + 1];
        float w0 = csr_w[j], w1 = csr_w[j + 1];
        float2 v0 = *(const float2*)&xin[(size_t)s0 * D + 2 * lane];
        float2 v1 = *(const float2*)&xin[(size_t)s1 * D + 2 * lane];
        a0 += w0 * v0.x + w1 * v1.x;
        a1 += w0 * v0.y + w1 * v1.y;
    }
    if (j < end) {
        int s0 = csr_src[j];
        float w0 = csr_w[j];
        float2 v0 = *(const float2*)&xin[(size_t)s0 * D + 2 * lane];
        a0 += w0 * v0.x;
        a1 += w0 * v0.y;
    }
    *(float2*)&agg[(size_t)node * D + 2 * lane] = make_float2(a0, a1);
}

// ---------------- fused GraphConv linear: out = relu(A1@W1 + A2@W2 + b) ----------------
#define FMA4(acc, a, wv) { acc.x += (a) * (wv).x; acc.y += (a) * (wv).y; \
                           acc.z += (a) * (wv).z; acc.w += (a) * (wv).w; }

__global__ __launch_bounds__(256) void lin_kernel(const float* __restrict__ A1,
                                                  const float* __restrict__ A2,
                                                  const float* __restrict__ W1,
                                                  const float* __restrict__ W2,
                                                  const float* __restrict__ b,
                                                  float* __restrict__ out, int N) {
    __shared__ float As[KT][132];   // transposed A tile: [k][row]
    __shared__ float Ws[KT][D];     // [k][col]
    int tid = threadIdx.x;
    int r0 = blockIdx.x * 128;
    int ty4 = (tid >> 3) * 4;
    int tx16 = (tid & 7) * 16;

    float4 acc[4][4];
#pragma unroll
    for (int i = 0; i < 4; ++i)
#pragma unroll
        for (int j = 0; j < 4; ++j) acc[i][j] = make_float4(0.f, 0.f, 0.f, 0.f);

    for (int t = 0; t < 8; ++t) {
        const float* A = (t < 4) ? A1 : A2;
        const float* W = (t < 4) ? W1 : W2;
        int koff = (t & 3) * KT;
        __syncthreads();
#pragma unroll
        for (int i = 0; i < 4; ++i) {
            int f4 = tid + i * 256;
            int row = f4 >> 3;
            int c4 = f4 & 7;
            float4 v = make_float4(0.f, 0.f, 0.f, 0.f);
            if (r0 + row < N) v = *(const float4*)&A[(size_t)(r0 + row) * D + koff + c4 * 4];
            As[c4 * 4 + 0][row] = v.x;
            As[c4 * 4 + 1][row] = v.y;
            As[c4 * 4 + 2][row] = v.z;
            As[c4 * 4 + 3][row] = v.w;
        }
#pragma unroll
        for (int i = 0; i < 4; ++i) {
            int f4 = tid + i * 256;
            int k = f4 >> 5;
            int c4 = f4 & 31;
            *(float4*)&Ws[k][c4 * 4] = *(const float4*)&W[(size_t)(koff + k) * D + c4 * 4];
        }
        __syncthreads();
#pragma unroll 4
        for (int k = 0; k < KT; ++k) {
            float4 av = *(const float4*)&As[k][ty4];
            float4 w0 = *(const float4*)&Ws[k][tx16];
            float4 w1 = *(const float4*)&Ws[k][tx16 + 4];
            float4 w2 = *(const float4*)&Ws[k][tx16 + 8];
            float4 w3 = *(const float4*)&Ws[k][tx16 + 12];
            FMA4(acc[0][0], av.x, w0); FMA4(acc[0][1], av.x, w1);
            FMA4(acc[0][2], av.x, w2); FMA4(acc[0][3], av.x, w3);
            FMA4(acc[1][0], av.y, w0); FMA4(acc[1][1], av.y, w1);
            FMA4(acc[1][2], av.y, w2); FMA4(acc[1][3], av.y, w3);
            FMA4(acc[2][0], av.z, w0); FMA4(acc[2][1], av.z, w1);
            FMA4(acc[2][2], av.z, w2); FMA4(acc[2][3], av.z, w3);
            FMA4(acc[3][0], av.w, w0); FMA4(acc[3][1], av.w, w1);
            FMA4(acc[3][2], av.w, w2); FMA4(acc[3][3], av.w, w3);
        }
    }
    float4 bv[4];
#pragma unroll
    for (int j = 0; j < 4; ++j) bv[j] = *(const float4*)&b[tx16 + j * 4];
#pragma unroll
    for (int i = 0; i < 4; ++i) {
        int r = r0 + ty4 + i;
        if (r < N) {
#pragma unroll
            for (int j = 0; j < 4; ++j) {
                float4 v;
                v.x = fmaxf(acc[i][j].x + bv[j].x, 0.f);
                v.y = fmaxf(acc[i][j].y + bv[j].y, 0.f);
                v.z = fmaxf(acc[i][j].z + bv[j].z, 0.f);
                v.w = fmaxf(acc[i][j].w + bv[j].w, 0.f);
                *(float4*)&out[(size_t)r * D + tx16 + j * 4] = v;
            }
        }
    }
}

// ---------------- Wc = W_m1 @ W_out ; bc = b_m1 @ W_out + b_out ----------------
__global__ __launch_bounds__(256) void smallmm_kernel(const float* __restrict__ Wm1,
                                                      const float* __restrict__ bm1,
                                                      const float* __restrict__ Wout,
                                                      const float* __restrict__ bout,
                                                      float* __restrict__ Wc,
                                                      float* __restrict__ bc) {
    int idx = blockIdx.x * 256 + threadIdx.x;
    if (blockIdx.x < 64) {
        int i = idx >> 7, j = idx & 127;
        float s = 0.f;
        for (int k = 0; k < 128; ++k) s += Wm1[i * 128 + k] * Wout[k * 128 + j];
        Wc[idx] = s;
    } else {
        int j = threadIdx.x;
        if (j < 128) {
            float s = bout[j];
            for (int k = 0; k < 128; ++k) s += bm1[k] * Wout[k * 128 + j];
            bc[j] = s;
        }
    }
}

// ---------------- s = h2@Wc + bc, softmax -> probs; den += deg[r]*||p||^2 ----------------
__global__ __launch_bounds__(256) void out_softmax_kernel(const float* __restrict__ h2,
                                                          const float* __restrict__ Wc,
                                                          const float* __restrict__ bc,
                                                          const float* __restrict__ deg,
                                                          float* __restrict__ probs,
                                                          float* __restrict__ accum, int N) {
    __shared__ float Rs[32][128];
    __shared__ float Ws[128 * 64];
    int tid = threadIdx.x;
    int wave = tid >> 6, lane = tid & 63;
    int r0 = blockIdx.x * 32;
#pragma unroll
    for (int i = 0; i < 4; ++i) {
        int f4 = tid + i * 256;
        int row = f4 >> 5;
        int c4 = f4 & 31;
        float4 v = make_float4(0.f, 0.f, 0.f, 0.f);
        if (r0 + row < N) v = *(const float4*)&h2[(size_t)(r0 + row) * D + c4 * 4];
        *(float4*)&Rs[row][c4 * 4] = v;
    }
    float lg[8][2];
#pragma unroll
    for (int h = 0; h < 2; ++h) {
        __syncthreads();
#pragma unroll
        for (int i = 0; i < 8; ++i) {
            int f4 = tid + i * 256;
            int k = f4 >> 4;
            int c4 = f4 & 15;
            *(float4*)&Ws[k * 64 + c4 * 4] = *(const float4*)&Wc[(size_t)k * 128 + h * 64 + c4 * 4];
        }
        __syncthreads();
        float bv = bc[h * 64 + lane];
        float a[8];
#pragma unroll
        for (int ri = 0; ri < 8; ++ri) a[ri] = bv;
        for (int k = 0; k < 128; ++k) {
            float wv = Ws[k * 64 + lane];
#pragma unroll
            for (int ri = 0; ri < 8; ++ri) a[ri] += Rs[wave + ri * 4][k] * wv;
        }
#pragma unroll
        for (int ri = 0; ri < 8; ++ri) lg[ri][h] = a[ri];
    }
    float den_local = 0.f;
#pragma unroll
    for (int ri = 0; ri < 8; ++ri) {
        int row = wave + ri * 4;
        int gr = r0 + row;
        float m = fmaxf(lg[ri][0], lg[ri][1]);
#pragma unroll
        for (int s = 32; s >= 1; s >>= 1) m = fmaxf(m, __shfl_xor(m, s));
        float e0 = expf(lg[ri][0] - m);
        float e1 = expf(lg[ri][1] - m);
        float sum = e0 + e1;
#pragma unroll
        for (int s = 32; s >= 1; s >>= 1) sum += __shfl_xor(sum, s);
        float inv = 1.f / sum;
        float p0 = e0 * inv, p1 = e1 * inv;
        float sq = p0 * p0 + p1 * p1;
#pragma unroll
        for (int s = 32; s >= 1; s >>= 1) sq += __shfl_xor(sq, s);
        if (gr < N) {
            probs[(size_t)gr * D + lane]      = p0;
            probs[(size_t)gr * D + 64 + lane] = p1;
            if (lane == 0) den_local += deg[gr] * sq;
        }
    }
    if (lane == 0 && den_local != 0.f) atomicAdd(&accum[1], den_local);
}

// ---------------- mincut_num via CSR: sum_n <p[n], sum_{e in row n} w_e p[src_e]> ----------------
__global__ __launch_bounds__(256) void num_csr_kernel(const float* __restrict__ probs,
                                                      const int* __restrict__ csr_src,
                                                      const float* __restrict__ csr_w,
                                                      const int* __restrict__ rowptr,
                                                      float* __restrict__ accum, int N) {
    int tid = threadIdx.x;
    int wave = tid >> 6, lane = tid & 63;
    float acc = 0.f;
    int stride = gridDim.x * 4;
    for (int node = blockIdx.x * 4 + wave; node < N; node += stride) {
        float2 pd = *(const float2*)&probs[(size_t)node * D + 2 * lane];
        int beg = rowptr[node], end = rowptr[node + 1];
        for (int j = beg; j < end; ++j) {
            int s = csr_src[j];
            float we = csr_w[j];
            float2 ps = *(const float2*)&probs[(size_t)s * D + 2 * lane];
            acc += we * (ps.x * pd.x + ps.y * pd.y);
        }
    }
#pragma unroll
    for (int m = 32; m >= 1; m >>= 1) acc += __shfl_xor(acc, m);
    if (lane == 0 && acc != 0.f) atomicAdd(&accum[0], acc);
}

// ---------------- ss += probs^T @ probs ----------------
__global__ __launch_bounds__(256) void ss_kernel(const float* __restrict__ probs,
                                                 float* __restrict__ ss, int N) {
    __shared__ float Ps[128];
    int tid = threadIdx.x;
    int a = tid >> 1;
    int boff = (tid & 1) * 64;
    float acc[64];
#pragma unroll
    for (int j = 0; j < 64; ++j) acc[j] = 0.f;
    for (int r = blockIdx.x; r < N; r += gridDim.x) {
        __syncthreads();
        if (tid < 32) *(float4*)&Ps[tid * 4] = *(const float4*)&probs[(size_t)r * D + tid * 4];
        __syncthreads();
        float pa = Ps[a];
#pragma unroll
        for (int j = 0; j < 64; ++j) acc[j] += pa * Ps[boff + j];
    }
#pragma unroll
    for (int j = 0; j < 64; ++j) atomicAdd(&ss[a * 128 + boff + j], acc[j]);
}

// ---------------- finalize: mc_loss, o_loss ----------------
__global__ __launch_bounds__(256) void finalize_kernel(const float* __restrict__ ss,
                                                       const float* __restrict__ accum,
                                                       float* __restrict__ out2) {
    int tid = threadIdx.x;
    __shared__ float wsum[4], wsum2[4];
    float s = 0.f;
    for (int i = tid; i < 16384; i += 256) { float v = ss[i]; s += v * v; }
#pragma unroll
    for (int m = 32; m >= 1; m >>= 1) s += __shfl_xor(s, m);
    if ((tid & 63) == 0) wsum[tid >> 6] = s;
    __syncthreads();
    float norm = sqrtf(wsum[0] + wsum[1] + wsum[2] + wsum[3]);
    float inv = 1.f / norm;
    const float rk = 0.08838834764831845f;  // 1/sqrt(128)
    float o = 0.f;
    for (int i = tid; i < 16384; i += 256) {
        int a = i >> 7, b = i & 127;
        float v = ss[i] * inv - (a == b ? rk : 0.f);
        o += v * v;
    }
#pragma unroll
    for (int m = 32; m >= 1; m >>= 1) o += __shfl_xor(o, m);
    if ((tid & 63) == 0) wsum2[tid >> 6] = o;
    __syncthreads();
    if (tid == 0) {
        out2[0] = -(accum[0] / accum[1]);
        out2[1] = sqrtf(wsum2[0] + wsum2[1] + wsum2[2] + wsum2[3]);
    }
}

extern "C" void kernel_launch(void* const* d_in, const int* in_sizes, int n_in,
                              void* d_out, int out_size, void* d_ws, size_t ws_size,
                              hipStream_t stream) {
    const float* x      = (const float*)d_in[0];
    const int*   ei     = (const int*)d_in[1];
    const float* w      = (const float*)d_in[2];
    const float* Wrel1  = (const float*)d_in[3];
    const float* brel1  = (const float*)d_in[4];
    const float* Wroot1 = (const float*)d_in[5];
    const float* Wrel2  = (const float*)d_in[6];
    const float* brel2  = (const float*)d_in[7];
    const float* Wroot2 = (const float*)d_in[8];
    const float* Wm1    = (const float*)d_in[9];
    const float* bm1    = (const float*)d_in[10];
    const float* Wout   = (const float*)d_in[11];
    const float* bout   = (const float*)d_in[12];

    int N = in_sizes[0] / D;
    int E = in_sizes[2];
    const int* src = ei;
    const int* dst = ei + E;

    float* probs = (float*)d_out;
    float* out2  = probs + (size_t)N * D;  // [mc_loss, o_loss]
    float* h2    = probs;                  // h2 in-place in d_out

    float* ws    = (float*)d_ws;
    float* agg   = ws;                       // N*D
    float* h1    = ws + (size_t)N * D;       // N*D
    float* Wc    = ws + (size_t)2 * N * D;   // 16384
    float* bc    = Wc + 16384;               // 128
    float* ssb   = bc + 128;                 // 16384   (memset block start)
    float* deg   = ssb + 16384;              // N
    float* accum = deg + N;                  // 2       (memset block end)
    float* csr_w = accum + 2;                // E
    int*   cnt   = (int*)(csr_w + E);        // N       (memset block start)
    int*   cur   = cnt + N;                  // N       (memset block end)
    int*   rowptr= cur + N;                  // N+1
    int*   aux   = rowptr + N + 1;           // 64
    int*   csr_src = aux + 64;               // E

    hipMemsetAsync(ssb, 0, (size_t)(16384 + N + 2) * sizeof(float), stream);
    hipMemsetAsync(cnt, 0, (size_t)2 * N * sizeof(int), stream);

    int eGrid = (E + 255) / 256;
    int nb = (N + 1023) / 1024;
    int linGrid = (N + 127) / 128;
    int nodeGrid = (N + 3) / 4;

    // CSR build (dst-keyed), reused by both gathers and num
    hist_kernel<<<eGrid, 256, 0, stream>>>(dst, cnt, E);
    scan_chunk_kernel<<<nb, 256, 0, stream>>>(cnt, rowptr, aux, N);
    scan_aux_kernel<<<1, 64, 0, stream>>>(aux, nb);
    add_off_kernel<<<(N + 255) / 256, 256, 0, stream>>>(rowptr, aux, N);
    fill_kernel<<<eGrid, 256, 0, stream>>>(src, dst, w, rowptr, cur, csr_src, csr_w, E);
    deg_kernel<<<eGrid, 256, 0, stream>>>(src, w, deg, E);

    gather_kernel<<<nodeGrid, 256, 0, stream>>>(x, csr_src, csr_w, rowptr, agg, N);
    lin_kernel<<<linGrid, 256, 0, stream>>>(agg, x, Wrel1, Wroot1, brel1, h1, N);
    gather_kernel<<<nodeGrid, 256, 0, stream>>>(h1, csr_src, csr_w, rowptr, agg, N);
    lin_kernel<<<linGrid, 256, 0, stream>>>(agg, h1, Wrel2, Wroot2, brel2, h2, N);
    smallmm_kernel<<<65, 256, 0, stream>>>(Wm1, bm1, Wout, bout, Wc, bc);
    out_softmax_kernel<<<(N + 31) / 32, 256, 0, stream>>>(h2, Wc, bc, deg, probs, accum, N);
    num_csr_kernel<<<2048, 256, 0, stream>>>(probs, csr_src, csr_w, rowptr, accum, N);
    ss_kernel<<<256, 256, 0, stream>>>(probs, ssb, N);
    finalize_kernel<<<1, 256, 0, stream>>>(ssb, accum, out2);
}

// Round 5
// 763.513 us; speedup vs baseline: 10.3911x; 1.4475x over previous
//
#include <hip/hip_runtime.h>
#include <hip/hip_bf16.h>

#define D 128
#define KT 32
#define SS_BLOCKS 256

// ---------------- degree: deg[src] += w ----------------
__global__ __launch_bounds__(256) void deg_kernel(const int* __restrict__ src,
                                                  const float* __restrict__ w,
                                                  float* __restrict__ deg, int E) {
    int e = blockIdx.x * 256 + threadIdx.x;
    if (e < E) atomicAdd(&deg[src[e]], w[e]);
}

// ---------------- CSR build: histogram of dst ----------------
__global__ __launch_bounds__(256) void hist_kernel(const int* __restrict__ dst,
                                                   int* __restrict__ cnt, int E) {
    int e = blockIdx.x * 256 + threadIdx.x;
    if (e < E) atomicAdd(&cnt[dst[e]], 1);
}

// ---------------- CSR build: per-1024-chunk inclusive scan ----------------
__global__ __launch_bounds__(256) void scan_chunk_kernel(const int* __restrict__ cnt,
                                                         int* __restrict__ rowptr,
                                                         int* __restrict__ aux, int N) {
    __shared__ int ts[256];
    int t = threadIdx.x;
    int base = blockIdx.x * 1024 + t * 4;
    int v[4], s = 0;
#pragma unroll
    for (int i = 0; i < 4; ++i) {
        v[i] = (base + i < N) ? cnt[base + i] : 0;
        s += v[i];
    }
    ts[t] = s;
    __syncthreads();
#pragma unroll
    for (int off = 1; off < 256; off <<= 1) {
        int add = (t >= off) ? ts[t - off] : 0;
        __syncthreads();
        ts[t] += add;
        __syncthreads();
    }
    int run = ts[t] - s;
#pragma unroll
    for (int i = 0; i < 4; ++i) {
        run += v[i];
        if (base + i < N) rowptr[base + i + 1] = run;
    }
    if (t == 255) aux[blockIdx.x] = ts[255];
}

__global__ void scan_aux_kernel(int* __restrict__ aux, int nb) {
    if (threadIdx.x == 0) {
        int s = 0;
        for (int i = 0; i < nb; ++i) { s += aux[i]; aux[i] = s; }
    }
}

__global__ __launch_bounds__(256) void add_off_kernel(int* __restrict__ rowptr,
                                                      const int* __restrict__ aux, int N) {
    int i = blockIdx.x * 256 + threadIdx.x;
    if (i == 0) rowptr[0] = 0;
    if (i < N) {
        int b = i >> 10;
        if (b > 0) rowptr[i + 1] += aux[b - 1];
    }
}

__global__ __launch_bounds__(256) void fill_kernel(const int* __restrict__ src,
                                                   const int* __restrict__ dst,
                                                   const float* __restrict__ w,
                                                   const int* __restrict__ rowptr,
                                                   int* __restrict__ cur,
                                                   int* __restrict__ csr_src,
                                                   float* __restrict__ csr_w, int E) {
    int e = blockIdx.x * 256 + threadIdx.x;
    if (e < E) {
        int d = dst[e];
        int pos = rowptr[d] + atomicAdd(&cur[d], 1);
        csr_src[pos] = src[e];
        csr_w[pos] = w[e];
    }
}

// ---------------- gather: agg[n] = sum_{e in row n} w_e * x[src_e] ----------------
__global__ __launch_bounds__(256) void gather_kernel(const float* __restrict__ xin,
                                                     const int* __restrict__ csr_src,
                                                     const float* __restrict__ csr_w,
                                                     const int* __restrict__ rowptr,
                                                     float* __restrict__ agg, int N) {
    int node = blockIdx.x * 4 + (threadIdx.x >> 6);
    if (node >= N) return;
    int lane = threadIdx.x & 63;
    int beg = rowptr[node], end = rowptr[node + 1];
    float a0 = 0.f, a1 = 0.f;
    int j = beg;
    for (; j + 1 < end; j += 2) {
        int s0 = csr_src[j], s1 = csr_src[j + 1];
        float w0 = csr_w[j], w1 = csr_w[j + 1];
        float2 v0 = *(const float2*)&xin[(size_t)s0 * D + 2 * lane];
        float2 v1 = *(const float2*)&xin[(size_t)s1 * D + 2 * lane];
        a0 += w0 * v0.x + w1 * v1.x;
        a1 += w0 * v0.y + w1 * v1.y;
    }
    if (j < end) {
        int s0 = csr_src[j];
        float w0 = csr_w[j];
        float2 v0 = *(const float2*)&xin[(size_t)s0 * D + 2 * lane];
        a0 += w0 * v0.x;
        a1 += w0 * v0.y;
    }
    *(float2*)&agg[(size_t)node * D + 2 * lane] = make_float2(a0, a1);
}

// ---------------- fused GraphConv linear: out = relu(A1@W1 + A2@W2 + b) ----------------
#define FMA4(acc, a, wv) { acc.x += (a) * (wv).x; acc.y += (a) * (wv).y; \
                           acc.z += (a) * (wv).z; acc.w += (a) * (wv).w; }

__global__ __launch_bounds__(256) void lin_kernel(const float* __restrict__ A1,
                                                  const float* __restrict__ A2,
                                                  const float* __restrict__ W1,
                                                  const float* __restrict__ W2,
                                                  const float* __restrict__ b,
                                                  float* __restrict__ out, int N) {
    __shared__ float As[KT][132];   // transposed A tile: [k][row]
    __shared__ float Ws[KT][D];     // [k][col]
    int tid = threadIdx.x;
    int r0 = blockIdx.x * 128;
    int ty4 = (tid >> 3) * 4;
    int tx16 = (tid & 7) * 16;

    float4 acc[4][4];
#pragma unroll
    for (int i = 0; i < 4; ++i)
#pragma unroll
        for (int j = 0; j < 4; ++j) acc[i][j] = make_float4(0.f, 0.f, 0.f, 0.f);

    for (int t = 0; t < 8; ++t) {
        const float* A = (t < 4) ? A1 : A2;
        const float* W = (t < 4) ? W1 : W2;
        int koff = (t & 3) * KT;
        __syncthreads();
#pragma unroll
        for (int i = 0; i < 4; ++i) {
            int f4 = tid + i * 256;
            int row = f4 >> 3;
            int c4 = f4 & 7;
            float4 v = make_float4(0.f, 0.f, 0.f, 0.f);
            if (r0 + row < N) v = *(const float4*)&A[(size_t)(r0 + row) * D + koff + c4 * 4];
            As[c4 * 4 + 0][row] = v.x;
            As[c4 * 4 + 1][row] = v.y;
            As[c4 * 4 + 2][row] = v.z;
            As[c4 * 4 + 3][row] = v.w;
        }
#pragma unroll
        for (int i = 0; i < 4; ++i) {
            int f4 = tid + i * 256;
            int k = f4 >> 5;
            int c4 = f4 & 31;
            *(float4*)&Ws[k][c4 * 4] = *(const float4*)&W[(size_t)(koff + k) * D + c4 * 4];
        }
        __syncthreads();
#pragma unroll 4
        for (int k = 0; k < KT; ++k) {
            float4 av = *(const float4*)&As[k][ty4];
            float4 w0 = *(const float4*)&Ws[k][tx16];
            float4 w1 = *(const float4*)&Ws[k][tx16 + 4];
            float4 w2 = *(const float4*)&Ws[k][tx16 + 8];
            float4 w3 = *(const float4*)&Ws[k][tx16 + 12];
            FMA4(acc[0][0], av.x, w0); FMA4(acc[0][1], av.x, w1);
            FMA4(acc[0][2], av.x, w2); FMA4(acc[0][3], av.x, w3);
            FMA4(acc[1][0], av.y, w0); FMA4(acc[1][1], av.y, w1);
            FMA4(acc[1][2], av.y, w2); FMA4(acc[1][3], av.y, w3);
            FMA4(acc[2][0], av.z, w0); FMA4(acc[2][1], av.z, w1);
            FMA4(acc[2][2], av.z, w2); FMA4(acc[2][3], av.z, w3);
            FMA4(acc[3][0], av.w, w0); FMA4(acc[3][1], av.w, w1);
            FMA4(acc[3][2], av.w, w2); FMA4(acc[3][3], av.w, w3);
        }
    }
    float4 bv[4];
#pragma unroll
    for (int j = 0; j < 4; ++j) bv[j] = *(const float4*)&b[tx16 + j * 4];
#pragma unroll
    for (int i = 0; i < 4; ++i) {
        int r = r0 + ty4 + i;
        if (r < N) {
#pragma unroll
            for (int j = 0; j < 4; ++j) {
                float4 v;
                v.x = fmaxf(acc[i][j].x + bv[j].x, 0.f);
                v.y = fmaxf(acc[i][j].y + bv[j].y, 0.f);
                v.z = fmaxf(acc[i][j].z + bv[j].z, 0.f);
                v.w = fmaxf(acc[i][j].w + bv[j].w, 0.f);
                *(float4*)&out[(size_t)r * D + tx16 + j * 4] = v;
            }
        }
    }
}

// ---------------- Wc = W_m1 @ W_out ; bc = b_m1 @ W_out + b_out ----------------
__global__ __launch_bounds__(256) void smallmm_kernel(const float* __restrict__ Wm1,
                                                      const float* __restrict__ bm1,
                                                      const float* __restrict__ Wout,
                                                      const float* __restrict__ bout,
                                                      float* __restrict__ Wc,
                                                      float* __restrict__ bc) {
    int idx = blockIdx.x * 256 + threadIdx.x;
    if (blockIdx.x < 64) {
        int i = idx >> 7, j = idx & 127;
        float s = 0.f;
        for (int k = 0; k < 128; ++k) s += Wm1[i * 128 + k] * Wout[k * 128 + j];
        Wc[idx] = s;
    } else {
        int j = threadIdx.x;
        if (j < 128) {
            float s = bout[j];
            for (int k = 0; k < 128; ++k) s += bm1[k] * Wout[k * 128 + j];
            bc[j] = s;
        }
    }
}

// ---------------- s = h2@Wc + bc, softmax -> probs; den += deg[r]*||p||^2 ----------------
__global__ __launch_bounds__(256) void out_softmax_kernel(const float* __restrict__ h2,
                                                          const float* __restrict__ Wc,
                                                          const float* __restrict__ bc,
                                                          const float* __restrict__ deg,
                                                          float* __restrict__ probs,
                                                          float* __restrict__ accum, int N) {
    __shared__ float Rs[32][128];
    __shared__ float Ws[128 * 64];
    int tid = threadIdx.x;
    int wave = tid >> 6, lane = tid & 63;
    int r0 = blockIdx.x * 32;
#pragma unroll
    for (int i = 0; i < 4; ++i) {
        int f4 = tid + i * 256;
        int row = f4 >> 5;
        int c4 = f4 & 31;
        float4 v = make_float4(0.f, 0.f, 0.f, 0.f);
        if (r0 + row < N) v = *(const float4*)&h2[(size_t)(r0 + row) * D + c4 * 4];
        *(float4*)&Rs[row][c4 * 4] = v;
    }
    float lg[8][2];
#pragma unroll
    for (int h = 0; h < 2; ++h) {
        __syncthreads();
#pragma unroll
        for (int i = 0; i < 8; ++i) {
            int f4 = tid + i * 256;
            int k = f4 >> 4;
            int c4 = f4 & 15;
            *(float4*)&Ws[k * 64 + c4 * 4] = *(const float4*)&Wc[(size_t)k * 128 + h * 64 + c4 * 4];
        }
        __syncthreads();
        float bv = bc[h * 64 + lane];
        float a[8];
#pragma unroll
        for (int ri = 0; ri < 8; ++ri) a[ri] = bv;
        for (int k = 0; k < 128; ++k) {
            float wv = Ws[k * 64 + lane];
#pragma unroll
            for (int ri = 0; ri < 8; ++ri) a[ri] += Rs[wave + ri * 4][k] * wv;
        }
#pragma unroll
        for (int ri = 0; ri < 8; ++ri) lg[ri][h] = a[ri];
    }
    float den_local = 0.f;
#pragma unroll
    for (int ri = 0; ri < 8; ++ri) {
        int row = wave + ri * 4;
        int gr = r0 + row;
        float m = fmaxf(lg[ri][0], lg[ri][1]);
#pragma unroll
        for (int s = 32; s >= 1; s >>= 1) m = fmaxf(m, __shfl_xor(m, s));
        float e0 = expf(lg[ri][0] - m);
        float e1 = expf(lg[ri][1] - m);
        float sum = e0 + e1;
#pragma unroll
        for (int s = 32; s >= 1; s >>= 1) sum += __shfl_xor(sum, s);
        float inv = 1.f / sum;
        float p0 = e0 * inv, p1 = e1 * inv;
        float sq = p0 * p0 + p1 * p1;
#pragma unroll
        for (int s = 32; s >= 1; s >>= 1) sq += __shfl_xor(sq, s);
        if (gr < N) {
            probs[(size_t)gr * D + lane]      = p0;
            probs[(size_t)gr * D + 64 + lane] = p1;
            if (lane == 0) den_local += deg[gr] * sq;
        }
    }
    if (lane == 0 && den_local != 0.f) atomicAdd(&accum[1], den_local);
}

// ---------------- mincut_num via CSR ----------------
__global__ __launch_bounds__(256) void num_csr_kernel(const float* __restrict__ probs,
                                                      const int* __restrict__ csr_src,
                                                      const float* __restrict__ csr_w,
                                                      const int* __restrict__ rowptr,
                                                      float* __restrict__ accum, int N) {
    int tid = threadIdx.x;
    int wave = tid >> 6, lane = tid & 63;
    float acc = 0.f;
    int stride = gridDim.x * 4;
    for (int node = blockIdx.x * 4 + wave; node < N; node += stride) {
        float2 pd = *(const float2*)&probs[(size_t)node * D + 2 * lane];
        int beg = rowptr[node], end = rowptr[node + 1];
        for (int j = beg; j < end; ++j) {
            int s = csr_src[j];
            float we = csr_w[j];
            float2 ps = *(const float2*)&probs[(size_t)s * D + 2 * lane];
            acc += we * (ps.x * pd.x + ps.y * pd.y);
        }
    }
#pragma unroll
    for (int m = 32; m >= 1; m >>= 1) acc += __shfl_xor(acc, m);
    if (lane == 0 && acc != 0.f) atomicAdd(&accum[0], acc);
}

// ---------------- ss partials: partial[blk] = sum of p_r^T p_r over block's rows ----------------
// 256 blocks; each thread owns an 8x8 tile (a0,b0); 32 rows staged per barrier;
// 4 x ds_read_b128 per row feeding 64 FMAs. Partials to global (no atomics).
__global__ __launch_bounds__(256) void ss_kernel(const float* __restrict__ probs,
                                                 float* __restrict__ partial, int N) {
    __shared__ float Ps[32][132];
    int tid = threadIdx.x;
    int a0 = (tid >> 4) * 8;
    int b0 = (tid & 15) * 8;
    float acc[8][8];
#pragma unroll
    for (int i = 0; i < 8; ++i)
#pragma unroll
        for (int j = 0; j < 8; ++j) acc[i][j] = 0.f;

    int rowsPerBlk = (N + gridDim.x - 1) / gridDim.x;
    int rbeg = blockIdx.x * rowsPerBlk;
    int rend = rbeg + rowsPerBlk;
    if (rend > N) rend = N;

    for (int c = rbeg; c < rend; c += 32) {
        int nr = rend - c;
        if (nr > 32) nr = 32;
        __syncthreads();
        for (int i = tid; i < nr * 32; i += 256) {
            int r = i >> 5, c4 = i & 31;
            *(float4*)&Ps[r][c4 * 4] = *(const float4*)&probs[(size_t)(c + r) * D + c4 * 4];
        }
        __syncthreads();
        for (int r = 0; r < nr; ++r) {
            float4 av0 = *(const float4*)&Ps[r][a0];
            float4 av1 = *(const float4*)&Ps[r][a0 + 4];
            float4 bv0 = *(const float4*)&Ps[r][b0];
            float4 bv1 = *(const float4*)&Ps[r][b0 + 4];
            float av[8] = {av0.x, av0.y, av0.z, av0.w, av1.x, av1.y, av1.z, av1.w};
            float bv[8] = {bv0.x, bv0.y, bv0.z, bv0.w, bv1.x, bv1.y, bv1.z, bv1.w};
#pragma unroll
            for (int i = 0; i < 8; ++i)
#pragma unroll
                for (int j = 0; j < 8; ++j) acc[i][j] += av[i] * bv[j];
        }
    }
    float* pb = partial + (size_t)blockIdx.x * 16384;
#pragma unroll
    for (int i = 0; i < 8; ++i) {
        *(float4*)&pb[(a0 + i) * 128 + b0]     = make_float4(acc[i][0], acc[i][1], acc[i][2], acc[i][3]);
        *(float4*)&pb[(a0 + i) * 128 + b0 + 4] = make_float4(acc[i][4], acc[i][5], acc[i][6], acc[i][7]);
    }
}

// ---------------- reduce partials -> ss ----------------
__global__ __launch_bounds__(256) void ss_reduce_kernel(const float* __restrict__ partial,
                                                        float* __restrict__ ss) {
    int i = blockIdx.x * 256 + threadIdx.x;   // 64 blocks x 256 = 16384
    float s = 0.f;
    for (int b = 0; b < SS_BLOCKS; ++b) s += partial[(size_t)b * 16384 + i];
    ss[i] = s;
}

// ---------------- finalize: mc_loss, o_loss ----------------
__global__ __launch_bounds__(256) void finalize_kernel(const float* __restrict__ ss,
                                                       const float* __restrict__ accum,
                                                       float* __restrict__ out2) {
    int tid = threadIdx.x;
    __shared__ float wsum[4], wsum2[4];
    float s = 0.f;
    for (int i = tid; i < 16384; i += 256) { float v = ss[i]; s += v * v; }
#pragma unroll
    for (int m = 32; m >= 1; m >>= 1) s += __shfl_xor(s, m);
    if ((tid & 63) == 0) wsum[tid >> 6] = s;
    __syncthreads();
    float norm = sqrtf(wsum[0] + wsum[1] + wsum[2] + wsum[3]);
    float inv = 1.f / norm;
    const float rk = 0.08838834764831845f;  // 1/sqrt(128)
    float o = 0.f;
    for (int i = tid; i < 16384; i += 256) {
        int a = i >> 7, b = i & 127;
        float v = ss[i] * inv - (a == b ? rk : 0.f);
        o += v * v;
    }
#pragma unroll
    for (int m = 32; m >= 1; m >>= 1) o += __shfl_xor(o, m);
    if ((tid & 63) == 0) wsum2[tid >> 6] = o;
    __syncthreads();
    if (tid == 0) {
        out2[0] = -(accum[0] / accum[1]);
        out2[1] = sqrtf(wsum2[0] + wsum2[1] + wsum2[2] + wsum2[3]);
    }
}

extern "C" void kernel_launch(void* const* d_in, const int* in_sizes, int n_in,
                              void* d_out, int out_size, void* d_ws, size_t ws_size,
                              hipStream_t stream) {
    const float* x      = (const float*)d_in[0];
    const int*   ei     = (const int*)d_in[1];
    const float* w      = (const float*)d_in[2];
    const float* Wrel1  = (const float*)d_in[3];
    const float* brel1  = (const float*)d_in[4];
    const float* Wroot1 = (const float*)d_in[5];
    const float* Wrel2  = (const float*)d_in[6];
    const float* brel2  = (const float*)d_in[7];
    const float* Wroot2 = (const float*)d_in[8];
    const float* Wm1    = (const float*)d_in[9];
    const float* bm1    = (const float*)d_in[10];
    const float* Wout   = (const float*)d_in[11];
    const float* bout   = (const float*)d_in[12];

    int N = in_sizes[0] / D;
    int E = in_sizes[2];
    const int* src = ei;
    const int* dst = ei + E;

    float* probs = (float*)d_out;
    float* out2  = probs + (size_t)N * D;  // [mc_loss, o_loss]
    float* h2    = probs;                  // h2 in-place in d_out

    float* ws    = (float*)d_ws;
    float* agg   = ws;                       // N*D  (later reused as ss partials: 256*16384 <= N*D)
    float* h1    = ws + (size_t)N * D;       // N*D
    float* Wc    = ws + (size_t)2 * N * D;   // 16384
    float* bc    = Wc + 16384;               // 128
    float* ssb   = bc + 128;                 // 16384
    float* deg   = ssb + 16384;              // N
    float* accum = deg + N;                  // 2
    float* csr_w = accum + 2;                // E
    int*   cnt   = (int*)(csr_w + E);        // N
    int*   cur   = cnt + N;                  // N
    int*   rowptr= cur + N;                  // N+1
    int*   aux   = rowptr + N + 1;           // 64
    int*   csr_src = aux + 64;               // E

    hipMemsetAsync(deg, 0, (size_t)(N + 2) * sizeof(float), stream);
    hipMemsetAsync(cnt, 0, (size_t)2 * N * sizeof(int), stream);

    int eGrid = (E + 255) / 256;
    int nb = (N + 1023) / 1024;
    int linGrid = (N + 127) / 128;
    int nodeGrid = (N + 3) / 4;

    // CSR build (dst-keyed), reused by both gathers and num
    hist_kernel<<<eGrid, 256, 0, stream>>>(dst, cnt, E);
    scan_chunk_kernel<<<nb, 256, 0, stream>>>(cnt, rowptr, aux, N);
    scan_aux_kernel<<<1, 64, 0, stream>>>(aux, nb);
    add_off_kernel<<<(N + 255) / 256, 256, 0, stream>>>(rowptr, aux, N);
    fill_kernel<<<eGrid, 256, 0, stream>>>(src, dst, w, rowptr, cur, csr_src, csr_w, E);
    deg_kernel<<<eGrid, 256, 0, stream>>>(src, w, deg, E);

    gather_kernel<<<nodeGrid, 256, 0, stream>>>(x, csr_src, csr_w, rowptr, agg, N);
    lin_kernel<<<linGrid, 256, 0, stream>>>(agg, x, Wrel1, Wroot1, brel1, h1, N);
    gather_kernel<<<nodeGrid, 256, 0, stream>>>(h1, csr_src, csr_w, rowptr, agg, N);
    lin_kernel<<<linGrid, 256, 0, stream>>>(agg, h1, Wrel2, Wroot2, brel2, h2, N);
    smallmm_kernel<<<65, 256, 0, stream>>>(Wm1, bm1, Wout, bout, Wc, bc);
    out_softmax_kernel<<<(N + 31) / 32, 256, 0, stream>>>(h2, Wc, bc, deg, probs, accum, N);
    num_csr_kernel<<<2048, 256, 0, stream>>>(probs, csr_src, csr_w, rowptr, accum, N);
    ss_kernel<<<SS_BLOCKS, 256, 0, stream>>>(probs, agg, N);   // agg reused as partials
    ss_reduce_kernel<<<64, 256, 0, stream>>>(agg, ssb);
    finalize_kernel<<<1, 256, 0, stream>>>(ssb, accum, out2);
}

// Round 6
// 728.573 us; speedup vs baseline: 10.8894x; 1.0480x over previous
//
#include <hip/hip_runtime.h>
#include <hip/hip_bf16.h>

#define D 128
#define KT 32
#define SS_BLOCKS 256

// ---------------- fused: cnt[dst]++ and deg[src] += w ----------------
__global__ __launch_bounds__(256) void hist_deg_kernel(const int* __restrict__ src,
                                                       const int* __restrict__ dst,
                                                       const float* __restrict__ w,
                                                       int* __restrict__ cnt,
                                                       float* __restrict__ deg, int E) {
    int e = blockIdx.x * 256 + threadIdx.x;
    if (e < E) {
        atomicAdd(&cnt[dst[e]], 1);
        atomicAdd(&deg[src[e]], w[e]);
    }
}

// ---------------- CSR build: per-1024-chunk inclusive scan ----------------
__global__ __launch_bounds__(256) void scan_chunk_kernel(const int* __restrict__ cnt,
                                                         int* __restrict__ rowptr,
                                                         int* __restrict__ aux, int N) {
    __shared__ int ts[256];
    int t = threadIdx.x;
    int base = blockIdx.x * 1024 + t * 4;
    int v[4], s = 0;
#pragma unroll
    for (int i = 0; i < 4; ++i) {
        v[i] = (base + i < N) ? cnt[base + i] : 0;
        s += v[i];
    }
    ts[t] = s;
    __syncthreads();
#pragma unroll
    for (int off = 1; off < 256; off <<= 1) {
        int add = (t >= off) ? ts[t - off] : 0;
        __syncthreads();
        ts[t] += add;
        __syncthreads();
    }
    int run = ts[t] - s;
#pragma unroll
    for (int i = 0; i < 4; ++i) {
        run += v[i];
        if (base + i < N) rowptr[base + i + 1] = run;
    }
    if (t == 255) aux[blockIdx.x] = ts[255];
}

__global__ void scan_aux_kernel(int* __restrict__ aux, int nb) {
    if (threadIdx.x == 0) {
        int s = 0;
        for (int i = 0; i < nb; ++i) { s += aux[i]; aux[i] = s; }
    }
}

__global__ __launch_bounds__(256) void add_off_kernel(int* __restrict__ rowptr,
                                                      const int* __restrict__ aux, int N) {
    int i = blockIdx.x * 256 + threadIdx.x;
    if (i == 0) rowptr[0] = 0;
    if (i < N) {
        int b = i >> 10;
        if (b > 0) rowptr[i + 1] += aux[b - 1];
    }
}

__global__ __launch_bounds__(256) void fill_kernel(const int* __restrict__ src,
                                                   const int* __restrict__ dst,
                                                   const float* __restrict__ w,
                                                   const int* __restrict__ rowptr,
                                                   int* __restrict__ cur,
                                                   int* __restrict__ csr_src,
                                                   float* __restrict__ csr_w, int E) {
    int e = blockIdx.x * 256 + threadIdx.x;
    if (e < E) {
        int d = dst[e];
        int pos = rowptr[d] + atomicAdd(&cur[d], 1);
        csr_src[pos] = src[e];
        csr_w[pos] = w[e];
    }
}

// ---------------- gather: agg[n] = sum_{e in row n} w_e * x[src_e] ----------------
// Wave per node. Half-wave edge split: lanes 0-31 take even edge, 32-63 odd edge,
// each lane loads float4 (32 lanes = full 512B row). 2x unroll -> 4 edges in flight.
#define ACC4(acc, we, v) { acc.x += (we) * (v).x; acc.y += (we) * (v).y; \
                           acc.z += (we) * (v).z; acc.w += (we) * (v).w; }

__global__ __launch_bounds__(256) void gather_kernel(const float* __restrict__ xin,
                                                     const int* __restrict__ csr_src,
                                                     const float* __restrict__ csr_w,
                                                     const int* __restrict__ rowptr,
                                                     float* __restrict__ agg, int N) {
    int node = blockIdx.x * 4 + (threadIdx.x >> 6);
    if (node >= N) return;
    int lane = threadIdx.x & 63;
    int half = lane >> 5;
    int c4 = (lane & 31) * 4;
    int beg = rowptr[node], end = rowptr[node + 1];
    float4 a0 = make_float4(0.f, 0.f, 0.f, 0.f);
    float4 a1 = make_float4(0.f, 0.f, 0.f, 0.f);
    int j = beg;
    for (; j + 3 < end; j += 4) {
        int e0 = j + half, e1 = j + 2 + half;
        int s0 = csr_src[e0]; float w0 = csr_w[e0];
        int s1 = csr_src[e1]; float w1 = csr_w[e1];
        float4 v0 = *(const float4*)&xin[(size_t)s0 * D + c4];
        float4 v1 = *(const float4*)&xin[(size_t)s1 * D + c4];
        ACC4(a0, w0, v0);
        ACC4(a1, w1, v1);
    }
    if (j + 1 < end) {
        int e0 = j + half;
        int s0 = csr_src[e0]; float w0 = csr_w[e0];
        float4 v0 = *(const float4*)&xin[(size_t)s0 * D + c4];
        ACC4(a0, w0, v0);
        j += 2;
    }
    if (j < end && half == 0) {
        int s0 = csr_src[j]; float w0 = csr_w[j];
        float4 v0 = *(const float4*)&xin[(size_t)s0 * D + c4];
        ACC4(a0, w0, v0);
    }
    a0.x += a1.x; a0.y += a1.y; a0.z += a1.z; a0.w += a1.w;
    a0.x += __shfl_xor(a0.x, 32);
    a0.y += __shfl_xor(a0.y, 32);
    a0.z += __shfl_xor(a0.z, 32);
    a0.w += __shfl_xor(a0.w, 32);
    if (half == 0) *(float4*)&agg[(size_t)node * D + c4] = a0;
}

// ---------------- fused GraphConv linear: out = relu(A1@W1 + A2@W2 + b) ----------------
#define FMA4(acc, a, wv) { acc.x += (a) * (wv).x; acc.y += (a) * (wv).y; \
                           acc.z += (a) * (wv).z; acc.w += (a) * (wv).w; }

__global__ __launch_bounds__(256) void lin_kernel(const float* __restrict__ A1,
                                                  const float* __restrict__ A2,
                                                  const float* __restrict__ W1,
                                                  const float* __restrict__ W2,
                                                  const float* __restrict__ b,
                                                  float* __restrict__ out, int N) {
    __shared__ float As[KT][132];   // transposed A tile: [k][row]
    __shared__ float Ws[KT][D];     // [k][col]
    int tid = threadIdx.x;
    int r0 = blockIdx.x * 128;
    int ty4 = (tid >> 3) * 4;
    int tx16 = (tid & 7) * 16;

    float4 acc[4][4];
#pragma unroll
    for (int i = 0; i < 4; ++i)
#pragma unroll
        for (int j = 0; j < 4; ++j) acc[i][j] = make_float4(0.f, 0.f, 0.f, 0.f);

    for (int t = 0; t < 8; ++t) {
        const float* A = (t < 4) ? A1 : A2;
        const float* W = (t < 4) ? W1 : W2;
        int koff = (t & 3) * KT;
        __syncthreads();
#pragma unroll
        for (int i = 0; i < 4; ++i) {
            int f4 = tid + i * 256;
            int row = f4 >> 3;
            int c4 = f4 & 7;
            float4 v = make_float4(0.f, 0.f, 0.f, 0.f);
            if (r0 + row < N) v = *(const float4*)&A[(size_t)(r0 + row) * D + koff + c4 * 4];
            As[c4 * 4 + 0][row] = v.x;
            As[c4 * 4 + 1][row] = v.y;
            As[c4 * 4 + 2][row] = v.z;
            As[c4 * 4 + 3][row] = v.w;
        }
#pragma unroll
        for (int i = 0; i < 4; ++i) {
            int f4 = tid + i * 256;
            int k = f4 >> 5;
            int c4 = f4 & 31;
            *(float4*)&Ws[k][c4 * 4] = *(const float4*)&W[(size_t)(koff + k) * D + c4 * 4];
        }
        __syncthreads();
#pragma unroll 4
        for (int k = 0; k < KT; ++k) {
            float4 av = *(const float4*)&As[k][ty4];
            float4 w0 = *(const float4*)&Ws[k][tx16];
            float4 w1 = *(const float4*)&Ws[k][tx16 + 4];
            float4 w2 = *(const float4*)&Ws[k][tx16 + 8];
            float4 w3 = *(const float4*)&Ws[k][tx16 + 12];
            FMA4(acc[0][0], av.x, w0); FMA4(acc[0][1], av.x, w1);
            FMA4(acc[0][2], av.x, w2); FMA4(acc[0][3], av.x, w3);
            FMA4(acc[1][0], av.y, w0); FMA4(acc[1][1], av.y, w1);
            FMA4(acc[1][2], av.y, w2); FMA4(acc[1][3], av.y, w3);
            FMA4(acc[2][0], av.z, w0); FMA4(acc[2][1], av.z, w1);
            FMA4(acc[2][2], av.z, w2); FMA4(acc[2][3], av.z, w3);
            FMA4(acc[3][0], av.w, w0); FMA4(acc[3][1], av.w, w1);
            FMA4(acc[3][2], av.w, w2); FMA4(acc[3][3], av.w, w3);
        }
    }
    float4 bv[4];
#pragma unroll
    for (int j = 0; j < 4; ++j) bv[j] = *(const float4*)&b[tx16 + j * 4];
#pragma unroll
    for (int i = 0; i < 4; ++i) {
        int r = r0 + ty4 + i;
        if (r < N) {
#pragma unroll
            for (int j = 0; j < 4; ++j) {
                float4 v;
                v.x = fmaxf(acc[i][j].x + bv[j].x, 0.f);
                v.y = fmaxf(acc[i][j].y + bv[j].y, 0.f);
                v.z = fmaxf(acc[i][j].z + bv[j].z, 0.f);
                v.w = fmaxf(acc[i][j].w + bv[j].w, 0.f);
                *(float4*)&out[(size_t)r * D + tx16 + j * 4] = v;
            }
        }
    }
}

// ---------------- Wc = W_m1 @ W_out ; bc = b_m1 @ W_out + b_out ----------------
__global__ __launch_bounds__(256) void smallmm_kernel(const float* __restrict__ Wm1,
                                                      const float* __restrict__ bm1,
                                                      const float* __restrict__ Wout,
                                                      const float* __restrict__ bout,
                                                      float* __restrict__ Wc,
                                                      float* __restrict__ bc) {
    int idx = blockIdx.x * 256 + threadIdx.x;
    if (blockIdx.x < 64) {
        int i = idx >> 7, j = idx & 127;
        float s = 0.f;
        for (int k = 0; k < 128; ++k) s += Wm1[i * 128 + k] * Wout[k * 128 + j];
        Wc[idx] = s;
    } else {
        int j = threadIdx.x;
        if (j < 128) {
            float s = bout[j];
            for (int k = 0; k < 128; ++k) s += bm1[k] * Wout[k * 128 + j];
            bc[j] = s;
        }
    }
}

// ---------------- s = h2@Wc + bc, softmax -> probs; den += deg[r]*||p||^2 ----------------
__global__ __launch_bounds__(256) void out_softmax_kernel(const float* __restrict__ h2,
                                                          const float* __restrict__ Wc,
                                                          const float* __restrict__ bc,
                                                          const float* __restrict__ deg,
                                                          float* __restrict__ probs,
                                                          float* __restrict__ accum, int N) {
    __shared__ float Rs[32][128];
    __shared__ float Ws[128 * 64];
    int tid = threadIdx.x;
    int wave = tid >> 6, lane = tid & 63;
    int r0 = blockIdx.x * 32;
#pragma unroll
    for (int i = 0; i < 4; ++i) {
        int f4 = tid + i * 256;
        int row = f4 >> 5;
        int c4 = f4 & 31;
        float4 v = make_float4(0.f, 0.f, 0.f, 0.f);
        if (r0 + row < N) v = *(const float4*)&h2[(size_t)(r0 + row) * D + c4 * 4];
        *(float4*)&Rs[row][c4 * 4] = v;
    }
    float lg[8][2];
#pragma unroll
    for (int h = 0; h < 2; ++h) {
        __syncthreads();
#pragma unroll
        for (int i = 0; i < 8; ++i) {
            int f4 = tid + i * 256;
            int k = f4 >> 4;
            int c4 = f4 & 15;
            *(float4*)&Ws[k * 64 + c4 * 4] = *(const float4*)&Wc[(size_t)k * 128 + h * 64 + c4 * 4];
        }
        __syncthreads();
        float bv = bc[h * 64 + lane];
        float a[8];
#pragma unroll
        for (int ri = 0; ri < 8; ++ri) a[ri] = bv;
        for (int k = 0; k < 128; ++k) {
            float wv = Ws[k * 64 + lane];
#pragma unroll
            for (int ri = 0; ri < 8; ++ri) a[ri] += Rs[wave + ri * 4][k] * wv;
        }
#pragma unroll
        for (int ri = 0; ri < 8; ++ri) lg[ri][h] = a[ri];
    }
    float den_local = 0.f;
#pragma unroll
    for (int ri = 0; ri < 8; ++ri) {
        int row = wave + ri * 4;
        int gr = r0 + row;
        float m = fmaxf(lg[ri][0], lg[ri][1]);
#pragma unroll
        for (int s = 32; s >= 1; s >>= 1) m = fmaxf(m, __shfl_xor(m, s));
        float e0 = expf(lg[ri][0] - m);
        float e1 = expf(lg[ri][1] - m);
        float sum = e0 + e1;
#pragma unroll
        for (int s = 32; s >= 1; s >>= 1) sum += __shfl_xor(sum, s);
        float inv = 1.f / sum;
        float p0 = e0 * inv, p1 = e1 * inv;
        float sq = p0 * p0 + p1 * p1;
#pragma unroll
        for (int s = 32; s >= 1; s >>= 1) sq += __shfl_xor(sq, s);
        if (gr < N) {
            probs[(size_t)gr * D + lane]      = p0;
            probs[(size_t)gr * D + 64 + lane] = p1;
            if (lane == 0) den_local += deg[gr] * sq;
        }
    }
    if (lane == 0 && den_local != 0.f) atomicAdd(&accum[1], den_local);
}

// ---------------- mincut_num via CSR (half-wave float4, 4 edges in flight) ----------------
__global__ __launch_bounds__(256) void num_csr_kernel(const float* __restrict__ probs,
                                                      const int* __restrict__ csr_src,
                                                      const float* __restrict__ csr_w,
                                                      const int* __restrict__ rowptr,
                                                      float* __restrict__ accum, int N) {
    int tid = threadIdx.x;
    int wave = tid >> 6, lane = tid & 63;
    int half = lane >> 5;
    int c4 = (lane & 31) * 4;
    float acc = 0.f;
    int stride = gridDim.x * 4;
    for (int node = blockIdx.x * 4 + wave; node < N; node += stride) {
        float4 pd = *(const float4*)&probs[(size_t)node * D + c4];
        int beg = rowptr[node], end = rowptr[node + 1];
        int j = beg;
        for (; j + 3 < end; j += 4) {
            int e0 = j + half, e1 = j + 2 + half;
            int s0 = csr_src[e0]; float w0 = csr_w[e0];
            int s1 = csr_src[e1]; float w1 = csr_w[e1];
            float4 p0 = *(const float4*)&probs[(size_t)s0 * D + c4];
            float4 p1 = *(const float4*)&probs[(size_t)s1 * D + c4];
            acc += w0 * (p0.x * pd.x + p0.y * pd.y + p0.z * pd.z + p0.w * pd.w)
                 + w1 * (p1.x * pd.x + p1.y * pd.y + p1.z * pd.z + p1.w * pd.w);
        }
        if (j + 1 < end) {
            int e0 = j + half;
            int s0 = csr_src[e0]; float w0 = csr_w[e0];
            float4 p0 = *(const float4*)&probs[(size_t)s0 * D + c4];
            acc += w0 * (p0.x * pd.x + p0.y * pd.y + p0.z * pd.z + p0.w * pd.w);
            j += 2;
        }
        if (j < end && half == 0) {
            int s0 = csr_src[j]; float w0 = csr_w[j];
            float4 p0 = *(const float4*)&probs[(size_t)s0 * D + c4];
            acc += w0 * (p0.x * pd.x + p0.y * pd.y + p0.z * pd.z + p0.w * pd.w);
        }
    }
#pragma unroll
    for (int m = 32; m >= 1; m >>= 1) acc += __shfl_xor(acc, m);
    if (lane == 0 && acc != 0.f) atomicAdd(&accum[0], acc);
}

// ---------------- ss partials: partial[blk] = sum of p_r^T p_r over block's rows ----------------
__global__ __launch_bounds__(256) void ss_kernel(const float* __restrict__ probs,
                                                 float* __restrict__ partial, int N) {
    __shared__ float Ps[32][132];
    int tid = threadIdx.x;
    int a0 = (tid >> 4) * 8;
    int b0 = (tid & 15) * 8;
    float acc[8][8];
#pragma unroll
    for (int i = 0; i < 8; ++i)
#pragma unroll
        for (int j = 0; j < 8; ++j) acc[i][j] = 0.f;

    int rowsPerBlk = (N + gridDim.x - 1) / gridDim.x;
    int rbeg = blockIdx.x * rowsPerBlk;
    int rend = rbeg + rowsPerBlk;
    if (rend > N) rend = N;

    for (int c = rbeg; c < rend; c += 32) {
        int nr = rend - c;
        if (nr > 32) nr = 32;
        __syncthreads();
        for (int i = tid; i < nr * 32; i += 256) {
            int r = i >> 5, c4 = i & 31;
            *(float4*)&Ps[r][c4 * 4] = *(const float4*)&probs[(size_t)(c + r) * D + c4 * 4];
        }
        __syncthreads();
        for (int r = 0; r < nr; ++r) {
            float4 av0 = *(const float4*)&Ps[r][a0];
            float4 av1 = *(const float4*)&Ps[r][a0 + 4];
            float4 bv0 = *(const float4*)&Ps[r][b0];
            float4 bv1 = *(const float4*)&Ps[r][b0 + 4];
            float av[8] = {av0.x, av0.y, av0.z, av0.w, av1.x, av1.y, av1.z, av1.w};
            float bv[8] = {bv0.x, bv0.y, bv0.z, bv0.w, bv1.x, bv1.y, bv1.z, bv1.w};
#pragma unroll
            for (int i = 0; i < 8; ++i)
#pragma unroll
                for (int j = 0; j < 8; ++j) acc[i][j] += av[i] * bv[j];
        }
    }
    float* pb = partial + (size_t)blockIdx.x * 16384;
#pragma unroll
    for (int i = 0; i < 8; ++i) {
        *(float4*)&pb[(a0 + i) * 128 + b0]     = make_float4(acc[i][0], acc[i][1], acc[i][2], acc[i][3]);
        *(float4*)&pb[(a0 + i) * 128 + b0 + 4] = make_float4(acc[i][4], acc[i][5], acc[i][6], acc[i][7]);
    }
}

// ---------------- reduce partials -> ss ----------------
__global__ __launch_bounds__(256) void ss_reduce_kernel(const float* __restrict__ partial,
                                                        float* __restrict__ ss) {
    int i = blockIdx.x * 256 + threadIdx.x;
    float s = 0.f;
    for (int b = 0; b < SS_BLOCKS; ++b) s += partial[(size_t)b * 16384 + i];
    ss[i] = s;
}

// ---------------- finalize: mc_loss, o_loss ----------------
__global__ __launch_bounds__(256) void finalize_kernel(const float* __restrict__ ss,
                                                       const float* __restrict__ accum,
                                                       float* __restrict__ out2) {
    int tid = threadIdx.x;
    __shared__ float wsum[4], wsum2[4];
    float s = 0.f;
    for (int i = tid; i < 16384; i += 256) { float v = ss[i]; s += v * v; }
#pragma unroll
    for (int m = 32; m >= 1; m >>= 1) s += __shfl_xor(s, m);
    if ((tid & 63) == 0) wsum[tid >> 6] = s;
    __syncthreads();
    float norm = sqrtf(wsum[0] + wsum[1] + wsum[2] + wsum[3]);
    float inv = 1.f / norm;
    const float rk = 0.08838834764831845f;  // 1/sqrt(128)
    float o = 0.f;
    for (int i = tid; i < 16384; i += 256) {
        int a = i >> 7, b = i & 127;
        float v = ss[i] * inv - (a == b ? rk : 0.f);
        o += v * v;
    }
#pragma unroll
    for (int m = 32; m >= 1; m >>= 1) o += __shfl_xor(o, m);
    if ((tid & 63) == 0) wsum2[tid >> 6] = o;
    __syncthreads();
    if (tid == 0) {
        out2[0] = -(accum[0] / accum[1]);
        out2[1] = sqrtf(wsum2[0] + wsum2[1] + wsum2[2] + wsum2[3]);
    }
}

extern "C" void kernel_launch(void* const* d_in, const int* in_sizes, int n_in,
                              void* d_out, int out_size, void* d_ws, size_t ws_size,
                              hipStream_t stream) {
    const float* x      = (const float*)d_in[0];
    const int*   ei     = (const int*)d_in[1];
    const float* w      = (const float*)d_in[2];
    const float* Wrel1  = (const float*)d_in[3];
    const float* brel1  = (const float*)d_in[4];
    const float* Wroot1 = (const float*)d_in[5];
    const float* Wrel2  = (const float*)d_in[6];
    const float* brel2  = (const float*)d_in[7];
    const float* Wroot2 = (const float*)d_in[8];
    const float* Wm1    = (const float*)d_in[9];
    const float* bm1    = (const float*)d_in[10];
    const float* Wout   = (const float*)d_in[11];
    const float* bout   = (const float*)d_in[12];

    int N = in_sizes[0] / D;
    int E = in_sizes[2];
    const int* src = ei;
    const int* dst = ei + E;

    float* probs = (float*)d_out;
    float* out2  = probs + (size_t)N * D;  // [mc_loss, o_loss]
    float* h2    = probs;                  // h2 in-place in d_out

    float* ws    = (float*)d_ws;
    float* agg   = ws;                       // N*D  (reused as ss partials)
    float* h1    = ws + (size_t)N * D;       // N*D
    float* Wc    = ws + (size_t)2 * N * D;   // 16384
    float* bc    = Wc + 16384;               // 128
    float* ssb   = bc + 128;                 // 16384
    float* deg   = ssb + 16384;              // N
    float* accum = deg + N;                  // 2
    float* csr_w = accum + 2;                // E
    int*   cnt   = (int*)(csr_w + E);        // N
    int*   cur   = cnt + N;                  // N
    int*   rowptr= cur + N;                  // N+1
    int*   aux   = rowptr + N + 1;           // 64
    int*   csr_src = aux + 64;               // E

    hipMemsetAsync(deg, 0, (size_t)(N + 2) * sizeof(float), stream);
    hipMemsetAsync(cnt, 0, (size_t)2 * N * sizeof(int), stream);

    int eGrid = (E + 255) / 256;
    int nb = (N + 1023) / 1024;
    int linGrid = (N + 127) / 128;
    int nodeGrid = (N + 3) / 4;

    // CSR build (dst-keyed), reused by both gathers and num
    hist_deg_kernel<<<eGrid, 256, 0, stream>>>(src, dst, w, cnt, deg, E);
    scan_chunk_kernel<<<nb, 256, 0, stream>>>(cnt, rowptr, aux, N);
    scan_aux_kernel<<<1, 64, 0, stream>>>(aux, nb);
    add_off_kernel<<<(N + 255) / 256, 256, 0, stream>>>(rowptr, aux, N);
    fill_kernel<<<eGrid, 256, 0, stream>>>(src, dst, w, rowptr, cur, csr_src, csr_w, E);

    gather_kernel<<<nodeGrid, 256, 0, stream>>>(x, csr_src, csr_w, rowptr, agg, N);
    lin_kernel<<<linGrid, 256, 0, stream>>>(agg, x, Wrel1, Wroot1, brel1, h1, N);
    gather_kernel<<<nodeGrid, 256, 0, stream>>>(h1, csr_src, csr_w, rowptr, agg, N);
    lin_kernel<<<linGrid, 256, 0, stream>>>(agg, h1, Wrel2, Wroot2, brel2, h2, N);
    smallmm_kernel<<<65, 256, 0, stream>>>(Wm1, bm1, Wout, bout, Wc, bc);
    out_softmax_kernel<<<(N + 31) / 32, 256, 0, stream>>>(h2, Wc, bc, deg, probs, accum, N);
    num_csr_kernel<<<2048, 256, 0, stream>>>(probs, csr_src, csr_w, rowptr, accum, N);
    ss_kernel<<<SS_BLOCKS, 256, 0, stream>>>(probs, agg, N);   // agg reused as partials
    ss_reduce_kernel<<<64, 256, 0, stream>>>(agg, ssb);
    finalize_kernel<<<1, 256, 0, stream>>>(ssb, accum, out2);
}

// Round 7
// 708.410 us; speedup vs baseline: 11.1993x; 1.0285x over previous
//
#include <hip/hip_runtime.h>
#include <hip/hip_bf16.h>

#define D 128
#define KT 32
#define SS_BLOCKS 256

__device__ __forceinline__ float bf2f(unsigned short u) {
    return __uint_as_float((unsigned)u << 16);
}

// ---------------- fused: cnt[dst]++ and deg[src] += w ----------------
__global__ __launch_bounds__(256) void hist_deg_kernel(const int* __restrict__ src,
                                                       const int* __restrict__ dst,
                                                       const float* __restrict__ w,
                                                       int* __restrict__ cnt,
                                                       float* __restrict__ deg, int E) {
    int e = blockIdx.x * 256 + threadIdx.x;
    if (e < E) {
        atomicAdd(&cnt[dst[e]], 1);
        atomicAdd(&deg[src[e]], w[e]);
    }
}

// ---------------- CSR build: per-1024-chunk inclusive scan ----------------
__global__ __launch_bounds__(256) void scan_chunk_kernel(const int* __restrict__ cnt,
                                                         int* __restrict__ rowptr,
                                                         int* __restrict__ aux, int N) {
    __shared__ int ts[256];
    int t = threadIdx.x;
    int base = blockIdx.x * 1024 + t * 4;
    int v[4], s = 0;
#pragma unroll
    for (int i = 0; i < 4; ++i) {
        v[i] = (base + i < N) ? cnt[base + i] : 0;
        s += v[i];
    }
    ts[t] = s;
    __syncthreads();
#pragma unroll
    for (int off = 1; off < 256; off <<= 1) {
        int add = (t >= off) ? ts[t - off] : 0;
        __syncthreads();
        ts[t] += add;
        __syncthreads();
    }
    int run = ts[t] - s;
#pragma unroll
    for (int i = 0; i < 4; ++i) {
        run += v[i];
        if (base + i < N) rowptr[base + i + 1] = run;
    }
    if (t == 255) aux[blockIdx.x] = ts[255];
}

__global__ void scan_aux_kernel(int* __restrict__ aux, int nb) {
    if (threadIdx.x == 0) {
        int s = 0;
        for (int i = 0; i < nb; ++i) { s += aux[i]; aux[i] = s; }
    }
}

__global__ __launch_bounds__(256) void add_off_kernel(int* __restrict__ rowptr,
                                                      const int* __restrict__ aux, int N) {
    int i = blockIdx.x * 256 + threadIdx.x;
    if (i == 0) rowptr[0] = 0;
    if (i < N) {
        int b = i >> 10;
        if (b > 0) rowptr[i + 1] += aux[b - 1];
    }
}

__global__ __launch_bounds__(256) void fill_kernel(const int* __restrict__ src,
                                                   const int* __restrict__ dst,
                                                   const float* __restrict__ w,
                                                   const int* __restrict__ rowptr,
                                                   int* __restrict__ cur,
                                                   int* __restrict__ csr_src,
                                                   float* __restrict__ csr_w, int E) {
    int e = blockIdx.x * 256 + threadIdx.x;
    if (e < E) {
        int d = dst[e];
        int pos = rowptr[d] + atomicAdd(&cur[d], 1);
        csr_src[pos] = src[e];
        csr_w[pos] = w[e];
    }
}

// ---------------- gather: agg[n] = sum_{e in row n} w_e * x[src_e] ----------------
// Wave per node; half-wave edge split (lanes 0-31 even edge, 32-63 odd), float4/lane.
// 8 edges in flight (4 row-load instructions), 4 independent accumulators.
#define ACC4(acc, we, v) { acc.x += (we) * (v).x; acc.y += (we) * (v).y; \
                           acc.z += (we) * (v).z; acc.w += (we) * (v).w; }

__global__ __launch_bounds__(256) void gather_kernel(const float* __restrict__ xin,
                                                     const int* __restrict__ csr_src,
                                                     const float* __restrict__ csr_w,
                                                     const int* __restrict__ rowptr,
                                                     float* __restrict__ agg, int N) {
    int node = blockIdx.x * 4 + (threadIdx.x >> 6);
    if (node >= N) return;
    int lane = threadIdx.x & 63;
    int half = lane >> 5;
    int c4 = (lane & 31) * 4;
    int beg = rowptr[node], end = rowptr[node + 1];
    float4 a0 = make_float4(0.f, 0.f, 0.f, 0.f);
    float4 a1 = make_float4(0.f, 0.f, 0.f, 0.f);
    float4 a2 = make_float4(0.f, 0.f, 0.f, 0.f);
    float4 a3 = make_float4(0.f, 0.f, 0.f, 0.f);
    int j = beg;
    for (; j + 7 < end; j += 8) {
        int e0 = j + half, e1 = j + 2 + half, e2 = j + 4 + half, e3 = j + 6 + half;
        int s0 = csr_src[e0]; float w0 = csr_w[e0];
        int s1 = csr_src[e1]; float w1 = csr_w[e1];
        int s2 = csr_src[e2]; float w2 = csr_w[e2];
        int s3 = csr_src[e3]; float w3 = csr_w[e3];
        float4 v0 = *(const float4*)&xin[(size_t)s0 * D + c4];
        float4 v1 = *(const float4*)&xin[(size_t)s1 * D + c4];
        float4 v2 = *(const float4*)&xin[(size_t)s2 * D + c4];
        float4 v3 = *(const float4*)&xin[(size_t)s3 * D + c4];
        ACC4(a0, w0, v0);
        ACC4(a1, w1, v1);
        ACC4(a2, w2, v2);
        ACC4(a3, w3, v3);
    }
    for (; j + 1 < end; j += 2) {
        int e0 = j + half;
        int s0 = csr_src[e0]; float w0 = csr_w[e0];
        float4 v0 = *(const float4*)&xin[(size_t)s0 * D + c4];
        ACC4(a0, w0, v0);
    }
    if (j < end && half == 0) {
        int s0 = csr_src[j]; float w0 = csr_w[j];
        float4 v0 = *(const float4*)&xin[(size_t)s0 * D + c4];
        ACC4(a0, w0, v0);
    }
    a0.x += a1.x + a2.x + a3.x;
    a0.y += a1.y + a2.y + a3.y;
    a0.z += a1.z + a2.z + a3.z;
    a0.w += a1.w + a2.w + a3.w;
    a0.x += __shfl_xor(a0.x, 32);
    a0.y += __shfl_xor(a0.y, 32);
    a0.z += __shfl_xor(a0.z, 32);
    a0.w += __shfl_xor(a0.w, 32);
    if (half == 0) *(float4*)&agg[(size_t)node * D + c4] = a0;
}

// ---------------- fused GraphConv linear: out = relu(A1@W1 + A2@W2 + b) ----------------
#define FMA4(acc, a, wv) { acc.x += (a) * (wv).x; acc.y += (a) * (wv).y; \
                           acc.z += (a) * (wv).z; acc.w += (a) * (wv).w; }

__global__ __launch_bounds__(256) void lin_kernel(const float* __restrict__ A1,
                                                  const float* __restrict__ A2,
                                                  const float* __restrict__ W1,
                                                  const float* __restrict__ W2,
                                                  const float* __restrict__ b,
                                                  float* __restrict__ out, int N) {
    __shared__ float As[KT][132];   // transposed A tile: [k][row]
    __shared__ float Ws[KT][D];     // [k][col]
    int tid = threadIdx.x;
    int r0 = blockIdx.x * 128;
    int ty4 = (tid >> 3) * 4;
    int tx16 = (tid & 7) * 16;

    float4 acc[4][4];
#pragma unroll
    for (int i = 0; i < 4; ++i)
#pragma unroll
        for (int j = 0; j < 4; ++j) acc[i][j] = make_float4(0.f, 0.f, 0.f, 0.f);

    for (int t = 0; t < 8; ++t) {
        const float* A = (t < 4) ? A1 : A2;
        const float* W = (t < 4) ? W1 : W2;
        int koff = (t & 3) * KT;
        __syncthreads();
#pragma unroll
        for (int i = 0; i < 4; ++i) {
            int f4 = tid + i * 256;
            int row = f4 >> 3;
            int c4 = f4 & 7;
            float4 v = make_float4(0.f, 0.f, 0.f, 0.f);
            if (r0 + row < N) v = *(const float4*)&A[(size_t)(r0 + row) * D + koff + c4 * 4];
            As[c4 * 4 + 0][row] = v.x;
            As[c4 * 4 + 1][row] = v.y;
            As[c4 * 4 + 2][row] = v.z;
            As[c4 * 4 + 3][row] = v.w;
        }
#pragma unroll
        for (int i = 0; i < 4; ++i) {
            int f4 = tid + i * 256;
            int k = f4 >> 5;
            int c4 = f4 & 31;
            *(float4*)&Ws[k][c4 * 4] = *(const float4*)&W[(size_t)(koff + k) * D + c4 * 4];
        }
        __syncthreads();
#pragma unroll 4
        for (int k = 0; k < KT; ++k) {
            float4 av = *(const float4*)&As[k][ty4];
            float4 w0 = *(const float4*)&Ws[k][tx16];
            float4 w1 = *(const float4*)&Ws[k][tx16 + 4];
            float4 w2 = *(const float4*)&Ws[k][tx16 + 8];
            float4 w3 = *(const float4*)&Ws[k][tx16 + 12];
            FMA4(acc[0][0], av.x, w0); FMA4(acc[0][1], av.x, w1);
            FMA4(acc[0][2], av.x, w2); FMA4(acc[0][3], av.x, w3);
            FMA4(acc[1][0], av.y, w0); FMA4(acc[1][1], av.y, w1);
            FMA4(acc[1][2], av.y, w2); FMA4(acc[1][3], av.y, w3);
            FMA4(acc[2][0], av.z, w0); FMA4(acc[2][1], av.z, w1);
            FMA4(acc[2][2], av.z, w2); FMA4(acc[2][3], av.z, w3);
            FMA4(acc[3][0], av.w, w0); FMA4(acc[3][1], av.w, w1);
            FMA4(acc[3][2], av.w, w2); FMA4(acc[3][3], av.w, w3);
        }
    }
    float4 bv[4];
#pragma unroll
    for (int j = 0; j < 4; ++j) bv[j] = *(const float4*)&b[tx16 + j * 4];
#pragma unroll
    for (int i = 0; i < 4; ++i) {
        int r = r0 + ty4 + i;
        if (r < N) {
#pragma unroll
            for (int j = 0; j < 4; ++j) {
                float4 v;
                v.x = fmaxf(acc[i][j].x + bv[j].x, 0.f);
                v.y = fmaxf(acc[i][j].y + bv[j].y, 0.f);
                v.z = fmaxf(acc[i][j].z + bv[j].z, 0.f);
                v.w = fmaxf(acc[i][j].w + bv[j].w, 0.f);
                *(float4*)&out[(size_t)r * D + tx16 + j * 4] = v;
            }
        }
    }
}

// ---------------- Wc = W_m1 @ W_out ; bc = b_m1 @ W_out + b_out ----------------
__global__ __launch_bounds__(256) void smallmm_kernel(const float* __restrict__ Wm1,
                                                      const float* __restrict__ bm1,
                                                      const float* __restrict__ Wout,
                                                      const float* __restrict__ bout,
                                                      float* __restrict__ Wc,
                                                      float* __restrict__ bc) {
    int idx = blockIdx.x * 256 + threadIdx.x;
    if (blockIdx.x < 64) {
        int i = idx >> 7, j = idx & 127;
        float s = 0.f;
        for (int k = 0; k < 128; ++k) s += Wm1[i * 128 + k] * Wout[k * 128 + j];
        Wc[idx] = s;
    } else {
        int j = threadIdx.x;
        if (j < 128) {
            float s = bout[j];
            for (int k = 0; k < 128; ++k) s += bm1[k] * Wout[k * 128 + j];
            bc[j] = s;
        }
    }
}

// ---------------- s = h2@Wc + bc, softmax -> probs (+bf16 copy); den accum ----------------
__global__ __launch_bounds__(256) void out_softmax_kernel(const float* __restrict__ h2,
                                                          const float* __restrict__ Wc,
                                                          const float* __restrict__ bc,
                                                          const float* __restrict__ deg,
                                                          float* __restrict__ probs,
                                                          unsigned short* __restrict__ pbh,
                                                          float* __restrict__ accum, int N) {
    __shared__ float Rs[32][128];
    __shared__ float Ws[128 * 64];
    int tid = threadIdx.x;
    int wave = tid >> 6, lane = tid & 63;
    int r0 = blockIdx.x * 32;
#pragma unroll
    for (int i = 0; i < 4; ++i) {
        int f4 = tid + i * 256;
        int row = f4 >> 5;
        int c4 = f4 & 31;
        float4 v = make_float4(0.f, 0.f, 0.f, 0.f);
        if (r0 + row < N) v = *(const float4*)&h2[(size_t)(r0 + row) * D + c4 * 4];
        *(float4*)&Rs[row][c4 * 4] = v;
    }
    float lg[8][2];
#pragma unroll
    for (int h = 0; h < 2; ++h) {
        __syncthreads();
#pragma unroll
        for (int i = 0; i < 8; ++i) {
            int f4 = tid + i * 256;
            int k = f4 >> 4;
            int c4 = f4 & 15;
            *(float4*)&Ws[k * 64 + c4 * 4] = *(const float4*)&Wc[(size_t)k * 128 + h * 64 + c4 * 4];
        }
        __syncthreads();
        float bv = bc[h * 64 + lane];
        float a[8];
#pragma unroll
        for (int ri = 0; ri < 8; ++ri) a[ri] = bv;
        for (int k = 0; k < 128; ++k) {
            float wv = Ws[k * 64 + lane];
#pragma unroll
            for (int ri = 0; ri < 8; ++ri) a[ri] += Rs[wave + ri * 4][k] * wv;
        }
#pragma unroll
        for (int ri = 0; ri < 8; ++ri) lg[ri][h] = a[ri];
    }
    float den_local = 0.f;
#pragma unroll
    for (int ri = 0; ri < 8; ++ri) {
        int row = wave + ri * 4;
        int gr = r0 + row;
        float m = fmaxf(lg[ri][0], lg[ri][1]);
#pragma unroll
        for (int s = 32; s >= 1; s >>= 1) m = fmaxf(m, __shfl_xor(m, s));
        float e0 = expf(lg[ri][0] - m);
        float e1 = expf(lg[ri][1] - m);
        float sum = e0 + e1;
#pragma unroll
        for (int s = 32; s >= 1; s >>= 1) sum += __shfl_xor(sum, s);
        float inv = 1.f / sum;
        float p0 = e0 * inv, p1 = e1 * inv;
        float sq = p0 * p0 + p1 * p1;
#pragma unroll
        for (int s = 32; s >= 1; s >>= 1) sq += __shfl_xor(sq, s);
        if (gr < N) {
            probs[(size_t)gr * D + lane]      = p0;
            probs[(size_t)gr * D + 64 + lane] = p1;
            unsigned u0 = __float_as_uint(p0), u1 = __float_as_uint(p1);
            pbh[(size_t)gr * D + lane]      = (unsigned short)((u0 + 0x8000u) >> 16);
            pbh[(size_t)gr * D + 64 + lane] = (unsigned short)((u1 + 0x8000u) >> 16);
            if (lane == 0) den_local += deg[gr] * sq;
        }
    }
    if (lane == 0 && den_local != 0.f) atomicAdd(&accum[1], den_local);
}

// ---------------- mincut_num via CSR: bf16 src rows, 8 edges in flight ----------------
__global__ __launch_bounds__(256) void num_csr_kernel(const float* __restrict__ probs,
                                                      const unsigned short* __restrict__ pbh,
                                                      const int* __restrict__ csr_src,
                                                      const float* __restrict__ csr_w,
                                                      const int* __restrict__ rowptr,
                                                      float* __restrict__ accum, int N) {
    int tid = threadIdx.x;
    int wave = tid >> 6, lane = tid & 63;
    int half = lane >> 5;
    int c4 = (lane & 31) * 4;
    float acc = 0.f;
    int stride = gridDim.x * 4;
    for (int node = blockIdx.x * 4 + wave; node < N; node += stride) {
        float4 pd = *(const float4*)&probs[(size_t)node * D + c4];
        int beg = rowptr[node], end = rowptr[node + 1];
        int j = beg;
        for (; j + 7 < end; j += 8) {
            int e0 = j + half, e1 = j + 2 + half, e2 = j + 4 + half, e3 = j + 6 + half;
            int s0 = csr_src[e0]; float w0 = csr_w[e0];
            int s1 = csr_src[e1]; float w1 = csr_w[e1];
            int s2 = csr_src[e2]; float w2 = csr_w[e2];
            int s3 = csr_src[e3]; float w3 = csr_w[e3];
            ushort4 q0 = *(const ushort4*)&pbh[(size_t)s0 * D + c4];
            ushort4 q1 = *(const ushort4*)&pbh[(size_t)s1 * D + c4];
            ushort4 q2 = *(const ushort4*)&pbh[(size_t)s2 * D + c4];
            ushort4 q3 = *(const ushort4*)&pbh[(size_t)s3 * D + c4];
            acc += w0 * (bf2f(q0.x) * pd.x + bf2f(q0.y) * pd.y + bf2f(q0.z) * pd.z + bf2f(q0.w) * pd.w);
            acc += w1 * (bf2f(q1.x) * pd.x + bf2f(q1.y) * pd.y + bf2f(q1.z) * pd.z + bf2f(q1.w) * pd.w);
            acc += w2 * (bf2f(q2.x) * pd.x + bf2f(q2.y) * pd.y + bf2f(q2.z) * pd.z + bf2f(q2.w) * pd.w);
            acc += w3 * (bf2f(q3.x) * pd.x + bf2f(q3.y) * pd.y + bf2f(q3.z) * pd.z + bf2f(q3.w) * pd.w);
        }
        for (; j + 1 < end; j += 2) {
            int e0 = j + half;
            int s0 = csr_src[e0]; float w0 = csr_w[e0];
            ushort4 q0 = *(const ushort4*)&pbh[(size_t)s0 * D + c4];
            acc += w0 * (bf2f(q0.x) * pd.x + bf2f(q0.y) * pd.y + bf2f(q0.z) * pd.z + bf2f(q0.w) * pd.w);
        }
        if (j < end && half == 0) {
            int s0 = csr_src[j]; float w0 = csr_w[j];
            ushort4 q0 = *(const ushort4*)&pbh[(size_t)s0 * D + c4];
            acc += w0 * (bf2f(q0.x) * pd.x + bf2f(q0.y) * pd.y + bf2f(q0.z) * pd.z + bf2f(q0.w) * pd.w);
        }
    }
#pragma unroll
    for (int m = 32; m >= 1; m >>= 1) acc += __shfl_xor(acc, m);
    if (lane == 0 && acc != 0.f) atomicAdd(&accum[0], acc);
}

// ---------------- ss partials ----------------
__global__ __launch_bounds__(256) void ss_kernel(const float* __restrict__ probs,
                                                 float* __restrict__ partial, int N) {
    __shared__ float Ps[32][132];
    int tid = threadIdx.x;
    int a0 = (tid >> 4) * 8;
    int b0 = (tid & 15) * 8;
    float acc[8][8];
#pragma unroll
    for (int i = 0; i < 8; ++i)
#pragma unroll
        for (int j = 0; j < 8; ++j) acc[i][j] = 0.f;

    int rowsPerBlk = (N + gridDim.x - 1) / gridDim.x;
    int rbeg = blockIdx.x * rowsPerBlk;
    int rend = rbeg + rowsPerBlk;
    if (rend > N) rend = N;

    for (int c = rbeg; c < rend; c += 32) {
        int nr = rend - c;
        if (nr > 32) nr = 32;
        __syncthreads();
        for (int i = tid; i < nr * 32; i += 256) {
            int r = i >> 5, c4 = i & 31;
            *(float4*)&Ps[r][c4 * 4] = *(const float4*)&probs[(size_t)(c + r) * D + c4 * 4];
        }
        __syncthreads();
        for (int r = 0; r < nr; ++r) {
            float4 av0 = *(const float4*)&Ps[r][a0];
            float4 av1 = *(const float4*)&Ps[r][a0 + 4];
            float4 bv0 = *(const float4*)&Ps[r][b0];
            float4 bv1 = *(const float4*)&Ps[r][b0 + 4];
            float av[8] = {av0.x, av0.y, av0.z, av0.w, av1.x, av1.y, av1.z, av1.w};
            float bv[8] = {bv0.x, bv0.y, bv0.z, bv0.w, bv1.x, bv1.y, bv1.z, bv1.w};
#pragma unroll
            for (int i = 0; i < 8; ++i)
#pragma unroll
                for (int j = 0; j < 8; ++j) acc[i][j] += av[i] * bv[j];
        }
    }
    float* pb = partial + (size_t)blockIdx.x * 16384;
#pragma unroll
    for (int i = 0; i < 8; ++i) {
        *(float4*)&pb[(a0 + i) * 128 + b0]     = make_float4(acc[i][0], acc[i][1], acc[i][2], acc[i][3]);
        *(float4*)&pb[(a0 + i) * 128 + b0 + 4] = make_float4(acc[i][4], acc[i][5], acc[i][6], acc[i][7]);
    }
}

// ---------------- reduce partials -> ss ----------------
__global__ __launch_bounds__(256) void ss_reduce_kernel(const float* __restrict__ partial,
                                                        float* __restrict__ ss) {
    int i = blockIdx.x * 256 + threadIdx.x;
    float s = 0.f;
    for (int b = 0; b < SS_BLOCKS; ++b) s += partial[(size_t)b * 16384 + i];
    ss[i] = s;
}

// ---------------- finalize: mc_loss, o_loss ----------------
__global__ __launch_bounds__(256) void finalize_kernel(const float* __restrict__ ss,
                                                       const float* __restrict__ accum,
                                                       float* __restrict__ out2) {
    int tid = threadIdx.x;
    __shared__ float wsum[4], wsum2[4];
    float s = 0.f;
    for (int i = tid; i < 16384; i += 256) { float v = ss[i]; s += v * v; }
#pragma unroll
    for (int m = 32; m >= 1; m >>= 1) s += __shfl_xor(s, m);
    if ((tid & 63) == 0) wsum[tid >> 6] = s;
    __syncthreads();
    float norm = sqrtf(wsum[0] + wsum[1] + wsum[2] + wsum[3]);
    float inv = 1.f / norm;
    const float rk = 0.08838834764831845f;  // 1/sqrt(128)
    float o = 0.f;
    for (int i = tid; i < 16384; i += 256) {
        int a = i >> 7, b = i & 127;
        float v = ss[i] * inv - (a == b ? rk : 0.f);
        o += v * v;
    }
#pragma unroll
    for (int m = 32; m >= 1; m >>= 1) o += __shfl_xor(o, m);
    if ((tid & 63) == 0) wsum2[tid >> 6] = o;
    __syncthreads();
    if (tid == 0) {
        out2[0] = -(accum[0] / accum[1]);
        out2[1] = sqrtf(wsum2[0] + wsum2[1] + wsum2[2] + wsum2[3]);
    }
}

extern "C" void kernel_launch(void* const* d_in, const int* in_sizes, int n_in,
                              void* d_out, int out_size, void* d_ws, size_t ws_size,
                              hipStream_t stream) {
    const float* x      = (const float*)d_in[0];
    const int*   ei     = (const int*)d_in[1];
    const float* w      = (const float*)d_in[2];
    const float* Wrel1  = (const float*)d_in[3];
    const float* brel1  = (const float*)d_in[4];
    const float* Wroot1 = (const float*)d_in[5];
    const float* Wrel2  = (const float*)d_in[6];
    const float* brel2  = (const float*)d_in[7];
    const float* Wroot2 = (const float*)d_in[8];
    const float* Wm1    = (const float*)d_in[9];
    const float* bm1    = (const float*)d_in[10];
    const float* Wout   = (const float*)d_in[11];
    const float* bout   = (const float*)d_in[12];

    int N = in_sizes[0] / D;
    int E = in_sizes[2];
    const int* src = ei;
    const int* dst = ei + E;

    float* probs = (float*)d_out;
    float* out2  = probs + (size_t)N * D;  // [mc_loss, o_loss]
    float* h2    = probs;                  // h2 in-place in d_out

    float* ws    = (float*)d_ws;
    float* agg   = ws;                       // N*D  (reused as ss partials)
    float* h1    = ws + (size_t)N * D;       // N*D  (reused as bf16 probs table after lin2)
    float* Wc    = ws + (size_t)2 * N * D;   // 16384
    float* bc    = Wc + 16384;               // 128
    float* ssb   = bc + 128;                 // 16384
    float* deg   = ssb + 16384;              // N
    float* accum = deg + N;                  // 2
    float* csr_w = accum + 2;                // E
    int*   cnt   = (int*)(csr_w + E);        // N
    int*   cur   = cnt + N;                  // N
    int*   rowptr= cur + N;                  // N+1
    int*   aux   = rowptr + N + 1;           // 64
    int*   csr_src = aux + 64;               // E

    unsigned short* pbh = (unsigned short*)h1;  // N*D bf16 (h1 dead after lin2)

    hipMemsetAsync(deg, 0, (size_t)(N + 2) * sizeof(float), stream);
    hipMemsetAsync(cnt, 0, (size_t)2 * N * sizeof(int), stream);

    int eGrid = (E + 255) / 256;
    int nb = (N + 1023) / 1024;
    int linGrid = (N + 127) / 128;
    int nodeGrid = (N + 3) / 4;

    // CSR build (dst-keyed), reused by both gathers and num
    hist_deg_kernel<<<eGrid, 256, 0, stream>>>(src, dst, w, cnt, deg, E);
    scan_chunk_kernel<<<nb, 256, 0, stream>>>(cnt, rowptr, aux, N);
    scan_aux_kernel<<<1, 64, 0, stream>>>(aux, nb);
    add_off_kernel<<<(N + 255) / 256, 256, 0, stream>>>(rowptr, aux, N);
    fill_kernel<<<eGrid, 256, 0, stream>>>(src, dst, w, rowptr, cur, csr_src, csr_w, E);

    gather_kernel<<<nodeGrid, 256, 0, stream>>>(x, csr_src, csr_w, rowptr, agg, N);
    lin_kernel<<<linGrid, 256, 0, stream>>>(agg, x, Wrel1, Wroot1, brel1, h1, N);
    gather_kernel<<<nodeGrid, 256, 0, stream>>>(h1, csr_src, csr_w, rowptr, agg, N);
    lin_kernel<<<linGrid, 256, 0, stream>>>(agg, h1, Wrel2, Wroot2, brel2, h2, N);
    smallmm_kernel<<<65, 256, 0, stream>>>(Wm1, bm1, Wout, bout, Wc, bc);
    out_softmax_kernel<<<(N + 31) / 32, 256, 0, stream>>>(h2, Wc, bc, deg, probs, pbh, accum, N);
    num_csr_kernel<<<2048, 256, 0, stream>>>(probs, pbh, csr_src, csr_w, rowptr, accum, N);
    ss_kernel<<<SS_BLOCKS, 256, 0, stream>>>(probs, agg, N);   // agg reused as partials
    ss_reduce_kernel<<<64, 256, 0, stream>>>(agg, ssb);
    finalize_kernel<<<1, 256, 0, stream>>>(ssb, accum, out2);
}

// Round 8
// 638.527 us; speedup vs baseline: 12.4250x; 1.1094x over previous
//
#include <hip/hip_runtime.h>
#include <hip/hip_bf16.h>

#define D 128
#define KT 32
#define SS_BLOCKS 256
#define NUM_BLOCKS 2048

__device__ __forceinline__ float bfl(unsigned u) { return __uint_as_float(u << 16); }
__device__ __forceinline__ float bfh(unsigned u) { return __uint_as_float(u & 0xffff0000u); }

// ---------------- fused: slot[e] = cnt[dst]++ ; deg[src] += w ----------------
__global__ __launch_bounds__(256) void hist_deg_kernel(const int* __restrict__ src,
                                                       const int* __restrict__ dst,
                                                       const float* __restrict__ w,
                                                       int* __restrict__ cnt,
                                                       float* __restrict__ deg,
                                                       int* __restrict__ slot, int E) {
    int e = blockIdx.x * 256 + threadIdx.x;
    if (e < E) {
        slot[e] = atomicAdd(&cnt[dst[e]], 1);
        atomicAdd(&deg[src[e]], w[e]);
    }
}

// ---------------- CSR build: per-1024-chunk inclusive scan ----------------
__global__ __launch_bounds__(256) void scan_chunk_kernel(const int* __restrict__ cnt,
                                                         int* __restrict__ rowptr,
                                                         int* __restrict__ aux, int N) {
    __shared__ int ts[256];
    int t = threadIdx.x;
    int base = blockIdx.x * 1024 + t * 4;
    int v[4], s = 0;
#pragma unroll
    for (int i = 0; i < 4; ++i) {
        v[i] = (base + i < N) ? cnt[base + i] : 0;
        s += v[i];
    }
    ts[t] = s;
    __syncthreads();
#pragma unroll
    for (int off = 1; off < 256; off <<= 1) {
        int add = (t >= off) ? ts[t - off] : 0;
        __syncthreads();
        ts[t] += add;
        __syncthreads();
    }
    int run = ts[t] - s;
#pragma unroll
    for (int i = 0; i < 4; ++i) {
        run += v[i];
        if (base + i < N) rowptr[base + i + 1] = run;
    }
    if (t == 255) aux[blockIdx.x] = ts[255];
}

__global__ void scan_aux_kernel(int* __restrict__ aux, int nb) {
    if (threadIdx.x == 0) {
        int s = 0;
        for (int i = 0; i < nb; ++i) { s += aux[i]; aux[i] = s; }
    }
}

__global__ __launch_bounds__(256) void add_off_kernel(int* __restrict__ rowptr,
                                                      const int* __restrict__ aux, int N) {
    int i = blockIdx.x * 256 + threadIdx.x;
    if (i == 0) rowptr[0] = 0;
    if (i < N) {
        int b = i >> 10;
        if (b > 0) rowptr[i + 1] += aux[b - 1];
    }
}

// ---------------- CSR fill (atomic-free: slot from hist) ----------------
__global__ __launch_bounds__(256) void fill_kernel(const int* __restrict__ src,
                                                   const int* __restrict__ dst,
                                                   const float* __restrict__ w,
                                                   const int* __restrict__ rowptr,
                                                   const int* __restrict__ slot,
                                                   int* __restrict__ csr_src,
                                                   float* __restrict__ csr_w, int E) {
    int e = blockIdx.x * 256 + threadIdx.x;
    if (e < E) {
        int pos = rowptr[dst[e]] + slot[e];
        csr_src[pos] = src[e];
        csr_w[pos] = w[e];
    }
}

// ---------------- gather: agg[n] = sum_{e in row n} w_e * x[src_e] ----------------
// Wave per node; half-wave edge split, float4/lane (32 lanes = 512B row).
// 16 edges in flight (8 row-load instructions), 8 accumulators.
#define ACC4(acc, we, v) { acc.x += (we) * (v).x; acc.y += (we) * (v).y; \
                           acc.z += (we) * (v).z; acc.w += (we) * (v).w; }

__global__ __launch_bounds__(256) void gather_kernel(const float* __restrict__ xin,
                                                     const int* __restrict__ csr_src,
                                                     const float* __restrict__ csr_w,
                                                     const int* __restrict__ rowptr,
                                                     float* __restrict__ agg, int N) {
    int node = blockIdx.x * 4 + (threadIdx.x >> 6);
    if (node >= N) return;
    int lane = threadIdx.x & 63;
    int half = lane >> 5;
    int c4 = (lane & 31) * 4;
    int beg = rowptr[node], end = rowptr[node + 1];
    float4 a[8];
#pragma unroll
    for (int i = 0; i < 8; ++i) a[i] = make_float4(0.f, 0.f, 0.f, 0.f);
    int j = beg;
    for (; j + 15 < end; j += 16) {
        int ei[8], si[8];
        float wi[8];
#pragma unroll
        for (int i = 0; i < 8; ++i) {
            ei[i] = j + 2 * i + half;
            si[i] = csr_src[ei[i]];
            wi[i] = csr_w[ei[i]];
        }
        float4 v[8];
#pragma unroll
        for (int i = 0; i < 8; ++i) v[i] = *(const float4*)&xin[(size_t)si[i] * D + c4];
#pragma unroll
        for (int i = 0; i < 8; ++i) ACC4(a[i], wi[i], v[i]);
    }
    for (; j + 7 < end; j += 8) {
#pragma unroll
        for (int i = 0; i < 4; ++i) {
            int e0 = j + 2 * i + half;
            int s0 = csr_src[e0]; float w0 = csr_w[e0];
            float4 v0 = *(const float4*)&xin[(size_t)s0 * D + c4];
            ACC4(a[i], w0, v0);
        }
    }
    for (; j + 1 < end; j += 2) {
        int e0 = j + half;
        int s0 = csr_src[e0]; float w0 = csr_w[e0];
        float4 v0 = *(const float4*)&xin[(size_t)s0 * D + c4];
        ACC4(a[0], w0, v0);
    }
    if (j < end && half == 0) {
        int s0 = csr_src[j]; float w0 = csr_w[j];
        float4 v0 = *(const float4*)&xin[(size_t)s0 * D + c4];
        ACC4(a[0], w0, v0);
    }
    float4 r = a[0];
#pragma unroll
    for (int i = 1; i < 8; ++i) { r.x += a[i].x; r.y += a[i].y; r.z += a[i].z; r.w += a[i].w; }
    r.x += __shfl_xor(r.x, 32);
    r.y += __shfl_xor(r.y, 32);
    r.z += __shfl_xor(r.z, 32);
    r.w += __shfl_xor(r.w, 32);
    if (half == 0) *(float4*)&agg[(size_t)node * D + c4] = r;
}

// ---------------- fused GraphConv linear: out = relu(A1@W1 + A2@W2 + b) ----------------
#define FMA4(acc, a, wv) { acc.x += (a) * (wv).x; acc.y += (a) * (wv).y; \
                           acc.z += (a) * (wv).z; acc.w += (a) * (wv).w; }

__global__ __launch_bounds__(256) void lin_kernel(const float* __restrict__ A1,
                                                  const float* __restrict__ A2,
                                                  const float* __restrict__ W1,
                                                  const float* __restrict__ W2,
                                                  const float* __restrict__ b,
                                                  float* __restrict__ out, int N) {
    __shared__ float As[KT][132];   // transposed A tile: [k][row]
    __shared__ float Ws[KT][D];     // [k][col]
    int tid = threadIdx.x;
    int r0 = blockIdx.x * 128;
    int ty4 = (tid >> 3) * 4;
    int tx16 = (tid & 7) * 16;

    float4 acc[4][4];
#pragma unroll
    for (int i = 0; i < 4; ++i)
#pragma unroll
        for (int j = 0; j < 4; ++j) acc[i][j] = make_float4(0.f, 0.f, 0.f, 0.f);

    for (int t = 0; t < 8; ++t) {
        const float* A = (t < 4) ? A1 : A2;
        const float* W = (t < 4) ? W1 : W2;
        int koff = (t & 3) * KT;
        __syncthreads();
#pragma unroll
        for (int i = 0; i < 4; ++i) {
            int f4 = tid + i * 256;
            int row = f4 >> 3;
            int c4 = f4 & 7;
            float4 v = make_float4(0.f, 0.f, 0.f, 0.f);
            if (r0 + row < N) v = *(const float4*)&A[(size_t)(r0 + row) * D + koff + c4 * 4];
            As[c4 * 4 + 0][row] = v.x;
            As[c4 * 4 + 1][row] = v.y;
            As[c4 * 4 + 2][row] = v.z;
            As[c4 * 4 + 3][row] = v.w;
        }
#pragma unroll
        for (int i = 0; i < 4; ++i) {
            int f4 = tid + i * 256;
            int k = f4 >> 5;
            int c4 = f4 & 31;
            *(float4*)&Ws[k][c4 * 4] = *(const float4*)&W[(size_t)(koff + k) * D + c4 * 4];
        }
        __syncthreads();
#pragma unroll 4
        for (int k = 0; k < KT; ++k) {
            float4 av = *(const float4*)&As[k][ty4];
            float4 w0 = *(const float4*)&Ws[k][tx16];
            float4 w1 = *(const float4*)&Ws[k][tx16 + 4];
            float4 w2 = *(const float4*)&Ws[k][tx16 + 8];
            float4 w3 = *(const float4*)&Ws[k][tx16 + 12];
            FMA4(acc[0][0], av.x, w0); FMA4(acc[0][1], av.x, w1);
            FMA4(acc[0][2], av.x, w2); FMA4(acc[0][3], av.x, w3);
            FMA4(acc[1][0], av.y, w0); FMA4(acc[1][1], av.y, w1);
            FMA4(acc[1][2], av.y, w2); FMA4(acc[1][3], av.y, w3);
            FMA4(acc[2][0], av.z, w0); FMA4(acc[2][1], av.z, w1);
            FMA4(acc[2][2], av.z, w2); FMA4(acc[2][3], av.z, w3);
            FMA4(acc[3][0], av.w, w0); FMA4(acc[3][1], av.w, w1);
            FMA4(acc[3][2], av.w, w2); FMA4(acc[3][3], av.w, w3);
        }
    }
    float4 bv[4];
#pragma unroll
    for (int j = 0; j < 4; ++j) bv[j] = *(const float4*)&b[tx16 + j * 4];
#pragma unroll
    for (int i = 0; i < 4; ++i) {
        int r = r0 + ty4 + i;
        if (r < N) {
#pragma unroll
            for (int j = 0; j < 4; ++j) {
                float4 v;
                v.x = fmaxf(acc[i][j].x + bv[j].x, 0.f);
                v.y = fmaxf(acc[i][j].y + bv[j].y, 0.f);
                v.z = fmaxf(acc[i][j].z + bv[j].z, 0.f);
                v.w = fmaxf(acc[i][j].w + bv[j].w, 0.f);
                *(float4*)&out[(size_t)r * D + tx16 + j * 4] = v;
            }
        }
    }
}

// ---------------- Wc = W_m1 @ W_out ; bc = b_m1 @ W_out + b_out ----------------
__global__ __launch_bounds__(256) void smallmm_kernel(const float* __restrict__ Wm1,
                                                      const float* __restrict__ bm1,
                                                      const float* __restrict__ Wout,
                                                      const float* __restrict__ bout,
                                                      float* __restrict__ Wc,
                                                      float* __restrict__ bc) {
    int idx = blockIdx.x * 256 + threadIdx.x;
    if (blockIdx.x < 64) {
        int i = idx >> 7, j = idx & 127;
        float s = 0.f;
        for (int k = 0; k < 128; ++k) s += Wm1[i * 128 + k] * Wout[k * 128 + j];
        Wc[idx] = s;
    } else {
        int j = threadIdx.x;
        if (j < 128) {
            float s = bout[j];
            for (int k = 0; k < 128; ++k) s += bm1[k] * Wout[k * 128 + j];
            bc[j] = s;
        }
    }
}

// ---------------- s = h2@Wc + bc, softmax -> probs (+bf16 copy); den accum ----------------
__global__ __launch_bounds__(256) void out_softmax_kernel(const float* __restrict__ h2,
                                                          const float* __restrict__ Wc,
                                                          const float* __restrict__ bc,
                                                          const float* __restrict__ deg,
                                                          float* __restrict__ probs,
                                                          unsigned short* __restrict__ pbh,
                                                          float* __restrict__ accum, int N) {
    __shared__ float Rs[32][128];
    __shared__ float Ws[128 * 64];
    int tid = threadIdx.x;
    int wave = tid >> 6, lane = tid & 63;
    int r0 = blockIdx.x * 32;
#pragma unroll
    for (int i = 0; i < 4; ++i) {
        int f4 = tid + i * 256;
        int row = f4 >> 5;
        int c4 = f4 & 31;
        float4 v = make_float4(0.f, 0.f, 0.f, 0.f);
        if (r0 + row < N) v = *(const float4*)&h2[(size_t)(r0 + row) * D + c4 * 4];
        *(float4*)&Rs[row][c4 * 4] = v;
    }
    float lg[8][2];
#pragma unroll
    for (int h = 0; h < 2; ++h) {
        __syncthreads();
#pragma unroll
        for (int i = 0; i < 8; ++i) {
            int f4 = tid + i * 256;
            int k = f4 >> 4;
            int c4 = f4 & 15;
            *(float4*)&Ws[k * 64 + c4 * 4] = *(const float4*)&Wc[(size_t)k * 128 + h * 64 + c4 * 4];
        }
        __syncthreads();
        float bv = bc[h * 64 + lane];
        float a[8];
#pragma unroll
        for (int ri = 0; ri < 8; ++ri) a[ri] = bv;
        for (int k = 0; k < 128; ++k) {
            float wv = Ws[k * 64 + lane];
#pragma unroll
            for (int ri = 0; ri < 8; ++ri) a[ri] += Rs[wave + ri * 4][k] * wv;
        }
#pragma unroll
        for (int ri = 0; ri < 8; ++ri) lg[ri][h] = a[ri];
    }
    float den_local = 0.f;
#pragma unroll
    for (int ri = 0; ri < 8; ++ri) {
        int row = wave + ri * 4;
        int gr = r0 + row;
        float m = fmaxf(lg[ri][0], lg[ri][1]);
#pragma unroll
        for (int s = 32; s >= 1; s >>= 1) m = fmaxf(m, __shfl_xor(m, s));
        float e0 = expf(lg[ri][0] - m);
        float e1 = expf(lg[ri][1] - m);
        float sum = e0 + e1;
#pragma unroll
        for (int s = 32; s >= 1; s >>= 1) sum += __shfl_xor(sum, s);
        float inv = 1.f / sum;
        float p0 = e0 * inv, p1 = e1 * inv;
        float sq = p0 * p0 + p1 * p1;
#pragma unroll
        for (int s = 32; s >= 1; s >>= 1) sq += __shfl_xor(sq, s);
        if (gr < N) {
            probs[(size_t)gr * D + lane]      = p0;
            probs[(size_t)gr * D + 64 + lane] = p1;
            unsigned u0 = __float_as_uint(p0), u1 = __float_as_uint(p1);
            pbh[(size_t)gr * D + lane]      = (unsigned short)((u0 + 0x8000u) >> 16);
            pbh[(size_t)gr * D + 64 + lane] = (unsigned short)((u1 + 0x8000u) >> 16);
            if (lane == 0) den_local += deg[gr] * sq;
        }
    }
    if (lane == 0 && den_local != 0.f) atomicAdd(&accum[1], den_local);
}

// ---------------- merged: ss partials (blocks [0,SS_BLOCKS)) + mincut_num (rest) ----------------
// num: quarter-wave rows (16 lanes x ushort8 = 256B bf16 row), 4 edges/instr,
// 4-instr unroll = 16 edges in flight.
__global__ __launch_bounds__(256) void num_ss_kernel(const float* __restrict__ probs,
                                                     const unsigned short* __restrict__ pbh,
                                                     const int* __restrict__ csr_src,
                                                     const float* __restrict__ csr_w,
                                                     const int* __restrict__ rowptr,
                                                     float* __restrict__ accum,
                                                     float* __restrict__ partial, int N) {
    int tid = threadIdx.x;
    if (blockIdx.x < SS_BLOCKS) {
        // ---- ss part ----
        __shared__ float Ps[32][132];
        int a0 = (tid >> 4) * 8;
        int b0 = (tid & 15) * 8;
        float acc[8][8];
#pragma unroll
        for (int i = 0; i < 8; ++i)
#pragma unroll
            for (int j = 0; j < 8; ++j) acc[i][j] = 0.f;

        int rowsPerBlk = (N + SS_BLOCKS - 1) / SS_BLOCKS;
        int rbeg = blockIdx.x * rowsPerBlk;
        int rend = rbeg + rowsPerBlk;
        if (rend > N) rend = N;

        for (int c = rbeg; c < rend; c += 32) {
            int nr = rend - c;
            if (nr > 32) nr = 32;
            __syncthreads();
            for (int i = tid; i < nr * 32; i += 256) {
                int r = i >> 5, c4 = i & 31;
                *(float4*)&Ps[r][c4 * 4] = *(const float4*)&probs[(size_t)(c + r) * D + c4 * 4];
            }
            __syncthreads();
            for (int r = 0; r < nr; ++r) {
                float4 av0 = *(const float4*)&Ps[r][a0];
                float4 av1 = *(const float4*)&Ps[r][a0 + 4];
                float4 bv0 = *(const float4*)&Ps[r][b0];
                float4 bv1 = *(const float4*)&Ps[r][b0 + 4];
                float av[8] = {av0.x, av0.y, av0.z, av0.w, av1.x, av1.y, av1.z, av1.w};
                float bv[8] = {bv0.x, bv0.y, bv0.z, bv0.w, bv1.x, bv1.y, bv1.z, bv1.w};
#pragma unroll
                for (int i = 0; i < 8; ++i)
#pragma unroll
                    for (int j = 0; j < 8; ++j) acc[i][j] += av[i] * bv[j];
            }
        }
        float* pb = partial + (size_t)blockIdx.x * 16384;
#pragma unroll
        for (int i = 0; i < 8; ++i) {
            *(float4*)&pb[(a0 + i) * 128 + b0]     = make_float4(acc[i][0], acc[i][1], acc[i][2], acc[i][3]);
            *(float4*)&pb[(a0 + i) * 128 + b0 + 4] = make_float4(acc[i][4], acc[i][5], acc[i][6], acc[i][7]);
        }
        return;
    }
    // ---- num part ----
    int bid = blockIdx.x - SS_BLOCKS;
    int wave = tid >> 6, lane = tid & 63;
    int q = lane >> 4;            // quarter 0..3
    int c8 = (lane & 15) * 8;     // 8 features per lane
    float acc = 0.f;
    int stride = NUM_BLOCKS * 4;
    for (int node = bid * 4 + wave; node < N; node += stride) {
        float4 pdA = *(const float4*)&probs[(size_t)node * D + c8];
        float4 pdB = *(const float4*)&probs[(size_t)node * D + c8 + 4];
        int beg = rowptr[node], end = rowptr[node + 1];
        int j = beg;
        for (; j + 15 < end; j += 16) {
            int si[4]; float wi[4]; uint4 qv[4];
#pragma unroll
            for (int i = 0; i < 4; ++i) {
                int e = j + 4 * i + q;
                si[i] = csr_src[e];
                wi[i] = csr_w[e];
            }
#pragma unroll
            for (int i = 0; i < 4; ++i) qv[i] = *(const uint4*)&pbh[(size_t)si[i] * D + c8];
#pragma unroll
            for (int i = 0; i < 4; ++i) {
                acc += wi[i] * (bfl(qv[i].x) * pdA.x + bfh(qv[i].x) * pdA.y
                              + bfl(qv[i].y) * pdA.z + bfh(qv[i].y) * pdA.w
                              + bfl(qv[i].z) * pdB.x + bfh(qv[i].z) * pdB.y
                              + bfl(qv[i].w) * pdB.z + bfh(qv[i].w) * pdB.w);
            }
        }
        for (; j + 3 < end; j += 4) {
            int e = j + q;
            int s0 = csr_src[e]; float w0 = csr_w[e];
            uint4 qv = *(const uint4*)&pbh[(size_t)s0 * D + c8];
            acc += w0 * (bfl(qv.x) * pdA.x + bfh(qv.x) * pdA.y
                       + bfl(qv.y) * pdA.z + bfh(qv.y) * pdA.w
                       + bfl(qv.z) * pdB.x + bfh(qv.z) * pdB.y
                       + bfl(qv.w) * pdB.z + bfh(qv.w) * pdB.w);
        }
        int rem = end - j;   // 0..3
        if (q < rem) {
            int e = j + q;
            int s0 = csr_src[e]; float w0 = csr_w[e];
            uint4 qv = *(const uint4*)&pbh[(size_t)s0 * D + c8];
            acc += w0 * (bfl(qv.x) * pdA.x + bfh(qv.x) * pdA.y
                       + bfl(qv.y) * pdA.z + bfh(qv.y) * pdA.w
                       + bfl(qv.z) * pdB.x + bfh(qv.z) * pdB.y
                       + bfl(qv.w) * pdB.z + bfh(qv.w) * pdB.w);
        }
    }
#pragma unroll
    for (int m = 32; m >= 1; m >>= 1) acc += __shfl_xor(acc, m);
    if (lane == 0 && acc != 0.f) atomicAdd(&accum[0], acc);
}

// ---------------- reduce partials -> ss ----------------
__global__ __launch_bounds__(256) void ss_reduce_kernel(const float* __restrict__ partial,
                                                        float* __restrict__ ss) {
    int i = blockIdx.x * 256 + threadIdx.x;
    float s = 0.f;
    for (int b = 0; b < SS_BLOCKS; ++b) s += partial[(size_t)b * 16384 + i];
    ss[i] = s;
}

// ---------------- finalize: mc_loss, o_loss ----------------
__global__ __launch_bounds__(256) void finalize_kernel(const float* __restrict__ ss,
                                                       const float* __restrict__ accum,
                                                       float* __restrict__ out2) {
    int tid = threadIdx.x;
    __shared__ float wsum[4], wsum2[4];
    float s = 0.f;
    for (int i = tid; i < 16384; i += 256) { float v = ss[i]; s += v * v; }
#pragma unroll
    for (int m = 32; m >= 1; m >>= 1) s += __shfl_xor(s, m);
    if ((tid & 63) == 0) wsum[tid >> 6] = s;
    __syncthreads();
    float norm = sqrtf(wsum[0] + wsum[1] + wsum[2] + wsum[3]);
    float inv = 1.f / norm;
    const float rk = 0.08838834764831845f;  // 1/sqrt(128)
    float o = 0.f;
    for (int i = tid; i < 16384; i += 256) {
        int a = i >> 7, b = i & 127;
        float v = ss[i] * inv - (a == b ? rk : 0.f);
        o += v * v;
    }
#pragma unroll
    for (int m = 32; m >= 1; m >>= 1) o += __shfl_xor(o, m);
    if ((tid & 63) == 0) wsum2[tid >> 6] = o;
    __syncthreads();
    if (tid == 0) {
        out2[0] = -(accum[0] / accum[1]);
        out2[1] = sqrtf(wsum2[0] + wsum2[1] + wsum2[2] + wsum2[3]);
    }
}

extern "C" void kernel_launch(void* const* d_in, const int* in_sizes, int n_in,
                              void* d_out, int out_size, void* d_ws, size_t ws_size,
                              hipStream_t stream) {
    const float* x      = (const float*)d_in[0];
    const int*   ei     = (const int*)d_in[1];
    const float* w      = (const float*)d_in[2];
    const float* Wrel1  = (const float*)d_in[3];
    const float* brel1  = (const float*)d_in[4];
    const float* Wroot1 = (const float*)d_in[5];
    const float* Wrel2  = (const float*)d_in[6];
    const float* brel2  = (const float*)d_in[7];
    const float* Wroot2 = (const float*)d_in[8];
    const float* Wm1    = (const float*)d_in[9];
    const float* bm1    = (const float*)d_in[10];
    const float* Wout   = (const float*)d_in[11];
    const float* bout   = (const float*)d_in[12];

    int N = in_sizes[0] / D;
    int E = in_sizes[2];
    const int* src = ei;
    const int* dst = ei + E;

    float* probs = (float*)d_out;
    float* out2  = probs + (size_t)N * D;  // [mc_loss, o_loss]
    float* h2    = probs;                  // h2 in-place in d_out

    float* ws    = (float*)d_ws;
    float* agg   = ws;                       // N*D  (reused as ss partials)
    float* h1    = ws + (size_t)N * D;       // N*D  (reused as bf16 probs table)
    float* Wc    = ws + (size_t)2 * N * D;   // 16384
    float* bc    = Wc + 16384;               // 128
    float* ssb   = bc + 128;                 // 16384
    float* deg   = ssb + 16384;              // N
    float* accum = deg + N;                  // 2
    float* csr_w = accum + 2;                // E
    int*   cnt   = (int*)(csr_w + E);        // N
    int*   rowptr= cnt + N;                  // N+1
    int*   aux   = rowptr + N + 1;           // 64
    int*   csr_src = aux + 64;               // E
    int*   slot  = csr_src + E;              // E

    unsigned short* pbh = (unsigned short*)h1;  // N*D bf16 (h1 dead after lin2)

    hipMemsetAsync(deg, 0, (size_t)(N + 2) * sizeof(float), stream);
    hipMemsetAsync(cnt, 0, (size_t)N * sizeof(int), stream);

    int eGrid = (E + 255) / 256;
    int nb = (N + 1023) / 1024;
    int linGrid = (N + 127) / 128;
    int nodeGrid = (N + 3) / 4;

    // CSR build (dst-keyed), reused by both gathers and num
    hist_deg_kernel<<<eGrid, 256, 0, stream>>>(src, dst, w, cnt, deg, slot, E);
    scan_chunk_kernel<<<nb, 256, 0, stream>>>(cnt, rowptr, aux, N);
    scan_aux_kernel<<<1, 64, 0, stream>>>(aux, nb);
    add_off_kernel<<<(N + 255) / 256, 256, 0, stream>>>(rowptr, aux, N);
    fill_kernel<<<eGrid, 256, 0, stream>>>(src, dst, w, rowptr, slot, csr_src, csr_w, E);

    gather_kernel<<<nodeGrid, 256, 0, stream>>>(x, csr_src, csr_w, rowptr, agg, N);
    lin_kernel<<<linGrid, 256, 0, stream>>>(agg, x, Wrel1, Wroot1, brel1, h1, N);
    gather_kernel<<<nodeGrid, 256, 0, stream>>>(h1, csr_src, csr_w, rowptr, agg, N);
    lin_kernel<<<linGrid, 256, 0, stream>>>(agg, h1, Wrel2, Wroot2, brel2, h2, N);
    smallmm_kernel<<<65, 256, 0, stream>>>(Wm1, bm1, Wout, bout, Wc, bc);
    out_softmax_kernel<<<(N + 31) / 32, 256, 0, stream>>>(h2, Wc, bc, deg, probs, pbh, accum, N);
    num_ss_kernel<<<SS_BLOCKS + NUM_BLOCKS, 256, 0, stream>>>(probs, pbh, csr_src, csr_w,
                                                              rowptr, accum, agg, N);
    ss_reduce_kernel<<<64, 256, 0, stream>>>(agg, ssb);
    finalize_kernel<<<1, 256, 0, stream>>>(ssb, accum, out2);
}